// Round 9
// baseline (399.657 us; speedup 1.0000x reference)
//
#include <hip/hip_runtime.h>

// ---------------- constants ----------------
// B=2048, K_OTH=16, K_LANE=32, N_OTH=32768, N_LANE=65536
// T=20 (hist/av), T_PRED=30, H=25, gates=100, NH=5, FO=5
//
// node id ranges: [0,2048) agent | [2048,4096) av | [4096,36864) others | [36864,102400) lanes
// ws layout (floats): ag_h @0 | ag_c @51200 | av_c @102400 | ot_c @153600 | ln_c @972800 | env_code @2611200
// out layout: predict [2048*30*2] @0, env_lane_info [2048*25] @122880

__device__ __forceinline__ float frcp(float x) { return __builtin_amdgcn_rcpf(x); }
__device__ __forceinline__ float fsig(float x) { return frcp(1.f + __expf(-x)); }
__device__ __forceinline__ float ftanh(float x) { return 1.f - 2.f * frcp(1.f + __expf(2.f * x)); }

// ---------------- encoder: unit-per-lane, 2 nodes/wave, weights in registers ----------------
// 2048 waves (512 blocks x 4 waves); wave W owns pairs [25W, 25W+25).
// __launch_bounds__(256,2): VGPR cap 256 -> ~160-reg working set stays in VGPRs,
// no AGPR juggling (r8 post-mortem: cap 128 caused ~2.5x VALU issue bloat).
__global__ __launch_bounds__(256, 2) void enc_kernel(
    const float* __restrict__ agent, const float* __restrict__ av,
    const float* __restrict__ oth,   const float* __restrict__ lane,
    const float* __restrict__ agWih, const float* __restrict__ agWhh, const float* __restrict__ agB,
    const float* __restrict__ avWih, const float* __restrict__ avWhh, const float* __restrict__ avB,
    const float* __restrict__ otWih, const float* __restrict__ otWhh, const float* __restrict__ otB,
    float* __restrict__ ws)
{
    __shared__ float hbuf[4][2][28];   // [wave][half][unit], rows 112B -> 16B aligned

    const int tid   = threadIdx.x;
    const int wv    = tid >> 6;
    const int lanei = tid & 63;
    const int half  = lanei >> 5;
    const int u     = lanei & 31;
    const bool act  = (u < 25);
    const int u2    = act ? u : 0;

    // zero the pad once (units 25..27)
    if (u >= 25 && u < 28) hbuf[wv][half][u] = 0.f;

    const int W  = blockIdx.x * 4 + wv;   // global wave id, 0..2047
    const int p0 = W * 25;
    const int p1 = p0 + 25;               // 2048*25 = 51200 pairs exactly

    int curTask = -1;
    float U[4][25], Wi0[4], Wi1[4], Bb[4];

#pragma unroll 1
    for (int p = p0; p < p1; ++p) {
        const int n = 2 * p + half;       // node id; both halves share the task (boundaries even)

        int task;
        if (n < 2048) task = 0;
        else if (n < 4096) task = 1;
        else if (n < 36864) task = 2;
        else task = 3;                    // lanes use the *agent* encoder (faithful to source bug)

        if (task != curTask) {            // wave-uniform
            curTask = task;
            const float* Wih; const float* Whh; const float* Bp;
            if (task == 1)      { Wih = avWih; Whh = avWhh; Bp = avB; }
            else if (task == 2) { Wih = otWih; Whh = otWhh; Bp = otB; }
            else                { Wih = agWih; Whh = agWhh; Bp = agB; }
#pragma unroll
            for (int r = 0; r < 4; ++r) {
                const int row = u2 + 25 * r;
#pragma unroll
                for (int k = 0; k < 25; ++k) U[r][k] = Whh[row * 25 + k];
                Wi0[r] = Wih[2 * row];
                Wi1[r] = Wih[2 * row + 1];
                Bb[r]  = Bp[row];
            }
        }

        const float* xp;
        if (task == 0)      xp = agent + n * 100;            // [50][2], first 20 steps
        else if (task == 1) xp = av   + (n - 2048)  * 40;
        else if (task == 2) xp = oth  + (n - 4096)  * 40;
        else                xp = lane + (n - 36864) * 40;

        // lane t (<20) holds the step-t input pair
        float2 xt = make_float2(0.f, 0.f);
        if (u < 20) xt = *reinterpret_cast<const float2*>(xp + 2 * u);

        float c = 0.f, ho = 0.f;
        float4 h4[7];
#pragma unroll
        for (int j = 0; j < 7; ++j) h4[j] = make_float4(0.f, 0.f, 0.f, 0.f);

#pragma unroll 1
        for (int t = 0; t < 20; ++t) {
            const float x0 = __shfl(xt.x, half * 32 + t, 64);
            const float x1 = __shfl(xt.y, half * 32 + t, 64);
            float g[4];
#pragma unroll
            for (int r = 0; r < 4; ++r) {
                // two partial accumulators halve the dependent-fma chain depth
                float accA = Bb[r] + Wi0[r] * x0;
                float accB = Wi1[r] * x1;
#pragma unroll
                for (int j = 0; j < 3; ++j) {
                    accA += U[r][4 * j]     * h4[j].x + U[r][4 * j + 1] * h4[j].y
                          + U[r][4 * j + 2] * h4[j].z + U[r][4 * j + 3] * h4[j].w;
                }
#pragma unroll
                for (int j = 3; j < 6; ++j) {
                    accB += U[r][4 * j]     * h4[j].x + U[r][4 * j + 1] * h4[j].y
                          + U[r][4 * j + 2] * h4[j].z + U[r][4 * j + 3] * h4[j].w;
                }
                accA += U[r][24] * h4[6].x;
                g[r] = accA + accB;
            }
            const float iv = fsig(g[0]);
            const float fv = fsig(g[1]);
            const float gv = ftanh(g[2]);
            const float ov = fsig(g[3]);
            c  = fv * c + iv * gv;
            ho = ov * ftanh(c);

            if (act) hbuf[wv][half][u] = ho;   // publish h(t+1)
            __builtin_amdgcn_wave_barrier();   // intra-wave LDS exchange (in-order per wave)
#pragma unroll
            for (int j = 0; j < 7; ++j)
                h4[j] = *reinterpret_cast<const float4*>(&hbuf[wv][half][4 * j]);
        }

        if (act) {
            if (task == 0) {
                ws[n * 25 + u]          = ho;   // ag_h
                ws[51200 + n * 25 + u]  = c;    // ag_c
            } else if (task == 1) {
                ws[102400 + (n - 2048) * 25 + u] = c;
            } else if (task == 2) {
                ws[153600 + (n - 4096) * 25 + u] = c;
            } else {
                ws[972800 + (n - 36864) * 25 + u] = c;
            }
        }
    }
}

// ---------------- GAT + env_lane_info: one block per env ----------------
__global__ __launch_bounds__(256) void gat_kernel(
    const float* __restrict__ ws,
    const float* __restrict__ gavW, const float* __restrict__ gavAl, const float* __restrict__ gavAr, const float* __restrict__ gavB,
    const float* __restrict__ gotW, const float* __restrict__ gotAl, const float* __restrict__ gotAr, const float* __restrict__ gotB,
    const float* __restrict__ glnW, const float* __restrict__ glnAl, const float* __restrict__ glnAr, const float* __restrict__ glnB,
    float* __restrict__ envcode, float* __restrict__ lane_out)
{
    __shared__ float X[50 * 25];   // 0: ag_c, 1: av_c, 2..17: ot srcs, 18..49: ln srcs
    __shared__ float F[52 * 25];   // 0: fs_av, 1: fd_av(unused), 2: fd_ot, 3: fd_ln, 4..19: fs_ot, 20..51: fs_ln
    __shared__ float er[10];       // [conv(ot=0,ln=1)][head]
    __shared__ float Eo[16 * 5];
    __shared__ float El[32 * 5];

    const int tid = threadIdx.x;
    const int b = blockIdx.x;
    const float* agc = ws + 51200;
    const float* avc = ws + 102400;
    const float* otc = ws + 153600;
    const float* lnc = ws + 972800;

    for (int i = tid; i < 1250; i += 256) {
        int r = i / 25, k = i - r * 25;
        float v;
        if (r == 0)      v = agc[b * 25 + k];
        else if (r == 1) v = avc[b * 25 + k];
        else if (r < 18) v = otc[(b * 16 + (r - 2)) * 25 + k];
        else             v = lnc[(b * 32 + (r - 18)) * 25 + k];
        X[i] = v;
    }
    __syncthreads();

    for (int d = tid; d < 1300; d += 256) {
        int row = d / 25, o = d - row * 25;
        const float* W; const float* xs;
        if (row == 0)      { W = gavW; xs = &X[1 * 25]; }
        else if (row == 1) { W = gavW; xs = &X[0]; }
        else if (row == 2) { W = gotW; xs = &X[0]; }
        else if (row == 3) { W = glnW; xs = &X[0]; }
        else if (row < 20) { W = gotW; xs = &X[(2 + row - 4) * 25]; }
        else               { W = glnW; xs = &X[(18 + row - 20) * 25]; }
        float acc = 0.f;
#pragma unroll
        for (int k = 0; k < 25; ++k) acc += W[o * 25 + k] * xs[k];
        F[row * 25 + o] = acc;
    }
    __syncthreads();

    if (tid < 10) {
        int conv = tid / 5, nn = tid - conv * 5;
        const float* ar = conv ? glnAr : gotAr;
        const float* fd = &F[(2 + conv) * 25];
        float acc = 0.f;
#pragma unroll
        for (int f = 0; f < 5; ++f) acc += fd[nn * 5 + f] * ar[nn * 5 + f];
        er[tid] = acc;
    }
    __syncthreads();

    for (int d = tid; d < 240; d += 256) {
        if (d < 80) {
            int i = d / 5, nn = d - i * 5;
            const float* fsrow = &F[(4 + i) * 25];
            float acc = er[nn];
#pragma unroll
            for (int f = 0; f < 5; ++f) acc += fsrow[nn * 5 + f] * gotAl[nn * 5 + f];
            Eo[d] = (acc > 0.f) ? acc : 0.2f * acc;
        } else {
            int d2 = d - 80;
            int i = d2 / 5, nn = d2 - i * 5;
            const float* fsrow = &F[(20 + i) * 25];
            float acc = er[5 + nn];
#pragma unroll
            for (int f = 0; f < 5; ++f) acc += fsrow[nn * 5 + f] * glnAl[nn * 5 + f];
            El[d2] = (acc > 0.f) ? acc : 0.2f * acc;
        }
    }
    __syncthreads();

    if (tid < 10) {
        int conv = tid / 5, nn = tid - conv * 5;
        if (conv == 0) {
            float m = -1e30f;
            for (int i = 0; i < 16; ++i) m = fmaxf(m, Eo[i * 5 + nn]);
            float s = 0.f;
            for (int i = 0; i < 16; ++i) s += __expf(Eo[i * 5 + nn] - m);
            float inv = frcp(s);
            for (int i = 0; i < 16; ++i) Eo[i * 5 + nn] = __expf(Eo[i * 5 + nn] - m) * inv;
        } else {
            float m = -1e30f;
            for (int i = 0; i < 32; ++i) m = fmaxf(m, El[i * 5 + nn]);
            float s = 0.f;
            for (int i = 0; i < 32; ++i) s += __expf(El[i * 5 + nn] - m);
            float inv = frcp(s);
            for (int i = 0; i < 32; ++i) El[i * 5 + nn] = __expf(El[i * 5 + nn] - m) * inv;
        }
    }
    __syncthreads();

    if (tid < 25) {
        const int o = tid, nn = o / 5;
        float v_av = F[o] + gavB[o];
        float s = 0.f;
        for (int i = 0; i < 16; ++i) s += Eo[i * 5 + nn] * F[(4 + i) * 25 + o];
        float v_ot = s + gotB[o];
        s = 0.f;
        for (int i = 0; i < 32; ++i) s += El[i * 5 + nn] * F[(20 + i) * 25 + o];
        float v_ln = s + glnB[o];
        envcode[b * 25 + o] = (v_av + v_ot + v_ln) * (1.f / 3.f);
        float m = 0.f;
        for (int i = 0; i < 32; ++i) m += X[(18 + i) * 25 + o];
        lane_out[b * 25 + o] = m * (1.f / 32.f);
    }
}

// ---------------- decoder: 25 lanes per env, 2 envs per wave, reg weights ----------------
__global__ __launch_bounds__(256) void dec_kernel(
    const float* __restrict__ ws,
    const float* __restrict__ deWih, const float* __restrict__ deWhh, const float* __restrict__ deB,
    const float* __restrict__ linW,  const float* __restrict__ linB,
    float* __restrict__ out)
{
    __shared__ float hbuf[8][28];
    const int tid  = threadIdx.x;
    const int lane = tid & 63;
    const int half = lane >> 5;
    const int u    = lane & 31;
    const int u2   = (u < 25) ? u : 0;
    const bool act = (u < 25);
    const int wglob = (blockIdx.x * 256 + tid) >> 6;
    const int b = wglob * 2 + half;                 // env id
    const int envloc = ((tid >> 6) << 1) + half;    // 0..7 within block

    float U[4][25], Wi[4], Bb[4];
#pragma unroll
    for (int r = 0; r < 4; ++r) {
        const int row = u2 + 25 * r;
#pragma unroll
        for (int k = 0; k < 25; ++k) U[r][k] = deWhh[row * 25 + k];
        Wi[r] = deWih[row];
        Bb[r] = deB[row];
    }
    const int j = u & 1;
    float lw[25];
#pragma unroll
    for (int k = 0; k < 25; ++k) lw[k] = linW[j * 25 + k];
    const float lb = linB[j];

    const float* agh = ws;
    const float* agc = ws + 51200;
    const float* env = ws + 2611200;

    float h[25];
#pragma unroll
    for (int k = 0; k < 25; ++k) h[k] = agh[b * 25 + k];
    float c_own = agc[b * 25 + u2] + env[b * 25 + u2];

    for (int t = 0; t < 30; ++t) {
        const float tt = 0.1f * (float)t;
        float g[4];
#pragma unroll
        for (int r = 0; r < 4; ++r) {
            float acc = Bb[r] + Wi[r] * tt;
#pragma unroll
            for (int k = 0; k < 25; ++k) acc += U[r][k] * h[k];
            g[r] = acc;
        }
        const float iv = fsig(g[0]);
        const float fv = fsig(g[1]);
        const float gv = ftanh(g[2]);
        const float ov = fsig(g[3]);
        c_own = fv * c_own + iv * gv;
        const float ho = ov * ftanh(c_own);
        if (act) hbuf[envloc][u] = ho;
        __builtin_amdgcn_wave_barrier();   // intra-wave LDS exchange; LDS is in-order per wave
#pragma unroll
        for (int k = 0; k < 25; ++k) h[k] = hbuf[envloc][k];
        float ov2 = lb;
#pragma unroll
        for (int k = 0; k < 25; ++k) ov2 += lw[k] * h[k];
        if (u < 2) out[b * 60 + t * 2 + u] = ov2;
    }
}

// ---------------- launch ----------------
extern "C" void kernel_launch(void* const* d_in, const int* in_sizes, int n_in,
                              void* d_out, int out_size, void* d_ws, size_t ws_size,
                              hipStream_t stream)
{
    const float* agent = (const float*)d_in[0];
    const float* av    = (const float*)d_in[1];
    const float* oth   = (const float*)d_in[2];
    const float* lane  = (const float*)d_in[3];
    const float* agWih = (const float*)d_in[4];
    const float* agWhh = (const float*)d_in[5];
    const float* agB   = (const float*)d_in[6];
    const float* avWih = (const float*)d_in[7];
    const float* avWhh = (const float*)d_in[8];
    const float* avB   = (const float*)d_in[9];
    const float* otWih = (const float*)d_in[10];
    const float* otWhh = (const float*)d_in[11];
    const float* otB   = (const float*)d_in[12];
    const float* deWih = (const float*)d_in[13];
    const float* deWhh = (const float*)d_in[14];
    const float* deB   = (const float*)d_in[15];
    const float* linW  = (const float*)d_in[16];
    const float* linB  = (const float*)d_in[17];
    const float* gavW  = (const float*)d_in[18];
    const float* gavAl = (const float*)d_in[19];
    const float* gavAr = (const float*)d_in[20];
    const float* gavB  = (const float*)d_in[21];
    const float* gotW  = (const float*)d_in[22];
    const float* gotAl = (const float*)d_in[23];
    const float* gotAr = (const float*)d_in[24];
    const float* gotB  = (const float*)d_in[25];
    const float* glnW  = (const float*)d_in[26];
    const float* glnAl = (const float*)d_in[27];
    const float* glnAr = (const float*)d_in[28];
    const float* glnB  = (const float*)d_in[29];
    // d_in[30]=others_dst, d_in[31]=lane_dst: implicit (i/16, i/32), not needed

    float* out = (float*)d_out;
    float* ws  = (float*)d_ws;

    enc_kernel<<<512, 256, 0, stream>>>(agent, av, oth, lane,
                                        agWih, agWhh, agB,
                                        avWih, avWhh, avB,
                                        otWih, otWhh, otB, ws);

    gat_kernel<<<2048, 256, 0, stream>>>(ws,
                                         gavW, gavAl, gavAr, gavB,
                                         gotW, gotAl, gotAr, gotB,
                                         glnW, glnAl, glnAr, glnB,
                                         ws + 2611200, out + 122880);

    dec_kernel<<<256, 256, 0, stream>>>(ws, deWih, deWhh, deB, linW, linB, out);
}

// Round 10
// 152.534 us; speedup vs baseline: 2.6201x; 2.6201x over previous
//
#include <hip/hip_runtime.h>

// ---------------- constants ----------------
// B=2048, K_OTH=16, K_LANE=32, N_OTH=32768, N_LANE=65536
// node id ranges: [0,2048) agent | [2048,4096) av | [4096,36864) others | [36864,102400) lanes
// ws layout (floats): ag_h @0 | ag_c @51200 | av_c @102400 | ot_c @153600 | ln_c @972800 | env_code @2611200
// out layout: predict [2048*30*2] @0, env_lane_info [2048*25] @122880
//
// enc (MFMA): one wave owns 16 nodes for all 20 steps. Gates[112 packed rows][16 nodes]
// computed as 7 MFMA tiles (16x16x32 bf16), K layout: k<25 = h, k=25,26 = x0,x1, k=27 = 1.0 (bias), k>=28 = 0.
// Packed gate row p = 4u + r  <->  torch row r*25 + u, so each lane's C regs hold unit u=4T+(lane>>4),
// gates r=0..3 for node n=lane&15 (C layout col=lane&15, row=(lane>>4)*4+reg, m89-verified).
// fp32 precision via 3-term bf16 split: Ahi*Bhi + Ahi*Blo + Alo*Bhi.

typedef __attribute__((ext_vector_type(8))) short s16x8;
typedef __attribute__((ext_vector_type(4))) float fx4;

__device__ __forceinline__ float frcp(float x) { return __builtin_amdgcn_rcpf(x); }
__device__ __forceinline__ float fsig(float x) { return frcp(1.f + __expf(-x)); }
__device__ __forceinline__ float ftanh(float x) { return 1.f - 2.f * frcp(1.f + __expf(2.f * x)); }

__device__ __forceinline__ unsigned bfhi(float f) {          // RNE f32->bf16 (as u16)
    unsigned b = __float_as_uint(f);
    return (b + 0x7FFFu + ((b >> 16) & 1u)) >> 16;
}
__device__ __forceinline__ float bfval(unsigned h) { return __uint_as_float(h << 16); }
__device__ __forceinline__ unsigned packsplit(float f) {     // lo16 = bf16 hi part, hi16 = bf16 residual
    unsigned h = bfhi(f);
    unsigned l = bfhi(f - bfval(h));
    return h | (l << 16);
}

struct BF { s16x8 hi, lo; };
__device__ __forceinline__ BF buildB(const unsigned* L, int q, int n) {
    unsigned rb[8];
#pragma unroll
    for (int e = 0; e < 8; ++e) rb[e] = L[(8 * q + e) * 17 + n];
    union { unsigned w[4]; s16x8 v; } H, Lo;
#pragma unroll
    for (int i = 0; i < 4; ++i) {
        H.w[i]  = __builtin_amdgcn_perm(rb[2 * i + 1], rb[2 * i], 0x05040100u); // hi(k even)|hi(k odd)<<16
        Lo.w[i] = __builtin_amdgcn_perm(rb[2 * i + 1], rb[2 * i], 0x07060302u); // lo parts
    }
    BF r; r.hi = H.v; r.lo = Lo.v; return r;
}

__global__ __launch_bounds__(256) void enc_kernel(
    const float* __restrict__ agent, const float* __restrict__ av,
    const float* __restrict__ oth,   const float* __restrict__ lane,
    const float* __restrict__ agWih, const float* __restrict__ agWhh, const float* __restrict__ agB,
    const float* __restrict__ avWih, const float* __restrict__ avWhh, const float* __restrict__ avB,
    const float* __restrict__ otWih, const float* __restrict__ otWhh, const float* __restrict__ otB,
    float* __restrict__ ws)
{
    __shared__ unsigned hlds[4][32 * 17];    // per wave: [k-slot 0..31][node 0..15], pad 17 words

    const int tid = threadIdx.x;
    const int wv  = tid >> 6;
    const int l   = tid & 63;
    const int n   = l & 15;     // node within group (and A local row, B/D col)
    const int q   = l >> 4;     // k-block (and unit offset j)
    unsigned* L = &hlds[wv][0];

    const int g0 = blockIdx.x * 4 + wv;      // group id 0..6399 (16 nodes each)
    int task;
    if (g0 < 128) task = 0;
    else if (g0 < 256) task = 1;
    else if (g0 < 2304) task = 2;
    else task = 3;                           // lanes use the *agent* encoder (faithful to source bug)

    const float* Whh; const float* Wih; const float* Bp;
    if (task == 1)      { Wih = avWih; Whh = avWhh; Bp = avB; }
    else if (task == 2) { Wih = otWih; Whh = otWhh; Bp = otB; }
    else                { Wih = agWih; Whh = agWhh; Bp = agB; }

    const int node = g0 * 16 + n;
    const float* xp;
    if (task == 0)      xp = agent + node * 100;
    else if (task == 1) xp = av   + (node - 2048)  * 40;
    else if (task == 2) xp = oth  + (node - 4096)  * 40;
    else                xp = lane + (node - 36864) * 40;

    // preload this node's x for steps 5q..5q+4 (lane (n,q) is the step-owner)
    float xv[10];
#pragma unroll
    for (int s = 0; s < 5; ++s) {
        float2 t2 = *reinterpret_cast<const float2*>(xp + 2 * (5 * q + s));
        xv[2 * s] = t2.x; xv[2 * s + 1] = t2.y;
    }

    // ---- A fragments (weights, loop-invariant): 7 tiles x (hi,lo) ----
    s16x8 Ahi[7], Alo[7];
#pragma unroll
    for (int T = 0; T < 7; ++T) {
        const int p = 16 * T + n;            // packed gate row
        const int r = p & 3;
        const int u = p >> 2;
        int row = r * 25 + u;                // torch row
        if (row > 99) row = 99;              // clamp fake rows (u>=25) in-bounds
        float w[8];
        if (q < 3) {
            const float* src = Whh + row * 25 + 8 * q;
#pragma unroll
            for (int e = 0; e < 8; ++e) w[e] = src[e];
        } else {
            w[0] = Whh[row * 25 + 24];
            w[1] = Wih[row * 2];
            w[2] = Wih[row * 2 + 1];
            w[3] = Bp[row];
            w[4] = w[5] = w[6] = w[7] = 0.f;
        }
#pragma unroll
        for (int e = 0; e < 8; ++e) {
            unsigned h = bfhi(w[e]);
            unsigned lo = bfhi(w[e] - bfval(h));
            Ahi[T][e] = (short)h;
            Alo[T][e] = (short)lo;
        }
    }

    // ---- init LDS: h(=0) slots, x(0), bias-one, zero pads ----
#pragma unroll
    for (int T = 0; T < 6; ++T) L[(4 * T + q) * 17 + n] = 0u;
    if (q == 0) {
        L[24 * 17 + n] = 0u;
        L[25 * 17 + n] = packsplit(xv[0]);
        L[26 * 17 + n] = packsplit(xv[1]);
    }
    if (q == 3) L[27 * 17 + n] = 0x00003F80u;    // 1.0 (hi=0x3F80, lo=0)
    L[(28 + q) * 17 + n] = 0u;
    __builtin_amdgcn_wave_barrier();

    BF Bf = buildB(L, q, n);

    float c[7], hv[7];
#pragma unroll
    for (int T = 0; T < 7; ++T) { c[T] = 0.f; hv[T] = 0.f; }

    const fx4 zero4 = {0.f, 0.f, 0.f, 0.f};

#pragma unroll 1
    for (int tt = 0; tt < 4; ++tt) {
#pragma unroll
        for (int s = 0; s < 5; ++s) {
            // gates for all 16 nodes: 7 tiles x 3 split-terms
            fx4 acc[7];
#pragma unroll
            for (int T = 0; T < 7; ++T) {
                fx4 a = __builtin_amdgcn_mfma_f32_16x16x32_bf16(Ahi[T], Bf.hi, zero4, 0, 0, 0);
                a = __builtin_amdgcn_mfma_f32_16x16x32_bf16(Ahi[T], Bf.lo, a, 0, 0, 0);
                a = __builtin_amdgcn_mfma_f32_16x16x32_bf16(Alo[T], Bf.hi, a, 0, 0, 0);
                acc[T] = a;
            }
            // cell update: lane owns unit u=4T+q of node n; acc[T] = {i,f,g,o}
#pragma unroll
            for (int T = 0; T < 7; ++T) {
                const float iv = fsig(acc[T][0]);
                const float fv = fsig(acc[T][1]);
                const float gv = ftanh(acc[T][2]);
                const float ov = fsig(acc[T][3]);
                c[T]  = fv * c[T] + iv * gv;
                hv[T] = ov * ftanh(c[T]);
            }
            const bool lastStep = (tt == 3) && (s == 4);
            if (!lastStep) {
                // publish h(t): u = 4T+q for T<6, plus u=24 by q==0 (never touch x/bias slots 25..27)
#pragma unroll
                for (int T = 0; T < 6; ++T) L[(4 * T + q) * 17 + n] = packsplit(hv[T]);
                if (q == 0) L[24 * 17 + n] = packsplit(hv[6]);
                // publish x(t+1) by its owner lane
                if (s < 4) {
                    if (q == tt) {
                        L[25 * 17 + n] = packsplit(xv[2 * (s + 1)]);
                        L[26 * 17 + n] = packsplit(xv[2 * (s + 1) + 1]);
                    }
                } else {
                    if (q == tt + 1) {
                        L[25 * 17 + n] = packsplit(xv[0]);
                        L[26 * 17 + n] = packsplit(xv[1]);
                    }
                }
                __builtin_amdgcn_wave_barrier();
                Bf = buildB(L, q, n);
            }
        }
    }

    // ---- store c (and h for agents) ----
    float* dst_c; float* dst_h = nullptr;
    if (task == 0)      { dst_h = ws + node * 25; dst_c = ws + 51200 + node * 25; }
    else if (task == 1) dst_c = ws + 102400 + (node - 2048) * 25;
    else if (task == 2) dst_c = ws + 153600 + (node - 4096) * 25;
    else                dst_c = ws + 972800 + (node - 36864) * 25;
#pragma unroll
    for (int T = 0; T < 7; ++T) {
        const int u = 4 * T + q;
        if (u < 25) {
            dst_c[u] = c[T];
            if (task == 0) dst_h[u] = hv[T];
        }
    }
}

// ---------------- GAT + env_lane_info: one block per env ----------------
__global__ __launch_bounds__(256) void gat_kernel(
    const float* __restrict__ ws,
    const float* __restrict__ gavW, const float* __restrict__ gavAl, const float* __restrict__ gavAr, const float* __restrict__ gavB,
    const float* __restrict__ gotW, const float* __restrict__ gotAl, const float* __restrict__ gotAr, const float* __restrict__ gotB,
    const float* __restrict__ glnW, const float* __restrict__ glnAl, const float* __restrict__ glnAr, const float* __restrict__ glnB,
    float* __restrict__ envcode, float* __restrict__ lane_out)
{
    __shared__ float X[50 * 25];   // 0: ag_c, 1: av_c, 2..17: ot srcs, 18..49: ln srcs
    __shared__ float F[52 * 25];   // 0: fs_av, 1: fd_av(unused), 2: fd_ot, 3: fd_ln, 4..19: fs_ot, 20..51: fs_ln
    __shared__ float er[10];       // [conv(ot=0,ln=1)][head]
    __shared__ float Eo[16 * 5];
    __shared__ float El[32 * 5];

    const int tid = threadIdx.x;
    const int b = blockIdx.x;
    const float* agc = ws + 51200;
    const float* avc = ws + 102400;
    const float* otc = ws + 153600;
    const float* lnc = ws + 972800;

    for (int i = tid; i < 1250; i += 256) {
        int r = i / 25, k = i - r * 25;
        float v;
        if (r == 0)      v = agc[b * 25 + k];
        else if (r == 1) v = avc[b * 25 + k];
        else if (r < 18) v = otc[(b * 16 + (r - 2)) * 25 + k];
        else             v = lnc[(b * 32 + (r - 18)) * 25 + k];
        X[i] = v;
    }
    __syncthreads();

    for (int d = tid; d < 1300; d += 256) {
        int row = d / 25, o = d - row * 25;
        const float* W; const float* xs;
        if (row == 0)      { W = gavW; xs = &X[1 * 25]; }
        else if (row == 1) { W = gavW; xs = &X[0]; }
        else if (row == 2) { W = gotW; xs = &X[0]; }
        else if (row == 3) { W = glnW; xs = &X[0]; }
        else if (row < 20) { W = gotW; xs = &X[(2 + row - 4) * 25]; }
        else               { W = glnW; xs = &X[(18 + row - 20) * 25]; }
        float acc = 0.f;
#pragma unroll
        for (int k = 0; k < 25; ++k) acc += W[o * 25 + k] * xs[k];
        F[row * 25 + o] = acc;
    }
    __syncthreads();

    if (tid < 10) {
        int conv = tid / 5, nn = tid - conv * 5;
        const float* ar = conv ? glnAr : gotAr;
        const float* fd = &F[(2 + conv) * 25];
        float acc = 0.f;
#pragma unroll
        for (int f = 0; f < 5; ++f) acc += fd[nn * 5 + f] * ar[nn * 5 + f];
        er[tid] = acc;
    }
    __syncthreads();

    for (int d = tid; d < 240; d += 256) {
        if (d < 80) {
            int i = d / 5, nn = d - i * 5;
            const float* fsrow = &F[(4 + i) * 25];
            float acc = er[nn];
#pragma unroll
            for (int f = 0; f < 5; ++f) acc += fsrow[nn * 5 + f] * gotAl[nn * 5 + f];
            Eo[d] = (acc > 0.f) ? acc : 0.2f * acc;
        } else {
            int d2 = d - 80;
            int i = d2 / 5, nn = d2 - i * 5;
            const float* fsrow = &F[(20 + i) * 25];
            float acc = er[5 + nn];
#pragma unroll
            for (int f = 0; f < 5; ++f) acc += fsrow[nn * 5 + f] * glnAl[nn * 5 + f];
            El[d2] = (acc > 0.f) ? acc : 0.2f * acc;
        }
    }
    __syncthreads();

    if (tid < 10) {
        int conv = tid / 5, nn = tid - conv * 5;
        if (conv == 0) {
            float m = -1e30f;
            for (int i = 0; i < 16; ++i) m = fmaxf(m, Eo[i * 5 + nn]);
            float s = 0.f;
            for (int i = 0; i < 16; ++i) s += __expf(Eo[i * 5 + nn] - m);
            float inv = frcp(s);
            for (int i = 0; i < 16; ++i) Eo[i * 5 + nn] = __expf(Eo[i * 5 + nn] - m) * inv;
        } else {
            float m = -1e30f;
            for (int i = 0; i < 32; ++i) m = fmaxf(m, El[i * 5 + nn]);
            float s = 0.f;
            for (int i = 0; i < 32; ++i) s += __expf(El[i * 5 + nn] - m);
            float inv = frcp(s);
            for (int i = 0; i < 32; ++i) El[i * 5 + nn] = __expf(El[i * 5 + nn] - m) * inv;
        }
    }
    __syncthreads();

    if (tid < 25) {
        const int o = tid, nn = o / 5;
        float v_av = F[o] + gavB[o];
        float s = 0.f;
        for (int i = 0; i < 16; ++i) s += Eo[i * 5 + nn] * F[(4 + i) * 25 + o];
        float v_ot = s + gotB[o];
        s = 0.f;
        for (int i = 0; i < 32; ++i) s += El[i * 5 + nn] * F[(20 + i) * 25 + o];
        float v_ln = s + glnB[o];
        envcode[b * 25 + o] = (v_av + v_ot + v_ln) * (1.f / 3.f);
        float m = 0.f;
        for (int i = 0; i < 32; ++i) m += X[(18 + i) * 25 + o];
        lane_out[b * 25 + o] = m * (1.f / 32.f);
    }
}

// ---------------- decoder: 25 lanes per env, 2 envs per wave, reg weights ----------------
__global__ __launch_bounds__(256) void dec_kernel(
    const float* __restrict__ ws,
    const float* __restrict__ deWih, const float* __restrict__ deWhh, const float* __restrict__ deB,
    const float* __restrict__ linW,  const float* __restrict__ linB,
    float* __restrict__ out)
{
    __shared__ float hbuf[8][28];
    const int tid  = threadIdx.x;
    const int lane = tid & 63;
    const int half = lane >> 5;
    const int u    = lane & 31;
    const int u2   = (u < 25) ? u : 0;
    const bool act = (u < 25);
    const int wglob = (blockIdx.x * 256 + tid) >> 6;
    const int b = wglob * 2 + half;                 // env id
    const int envloc = ((tid >> 6) << 1) + half;    // 0..7 within block

    float U[4][25], Wi[4], Bb[4];
#pragma unroll
    for (int r = 0; r < 4; ++r) {
        const int row = u2 + 25 * r;
#pragma unroll
        for (int k = 0; k < 25; ++k) U[r][k] = deWhh[row * 25 + k];
        Wi[r] = deWih[row];
        Bb[r] = deB[row];
    }
    const int j = u & 1;
    float lw[25];
#pragma unroll
    for (int k = 0; k < 25; ++k) lw[k] = linW[j * 25 + k];
    const float lb = linB[j];

    const float* agh = ws;
    const float* agc = ws + 51200;
    const float* env = ws + 2611200;

    float h[25];
#pragma unroll
    for (int k = 0; k < 25; ++k) h[k] = agh[b * 25 + k];
    float c_own = agc[b * 25 + u2] + env[b * 25 + u2];

    for (int t = 0; t < 30; ++t) {
        const float tt = 0.1f * (float)t;
        float g[4];
#pragma unroll
        for (int r = 0; r < 4; ++r) {
            float acc = Bb[r] + Wi[r] * tt;
#pragma unroll
            for (int k = 0; k < 25; ++k) acc += U[r][k] * h[k];
            g[r] = acc;
        }
        const float iv = fsig(g[0]);
        const float fv = fsig(g[1]);
        const float gv = ftanh(g[2]);
        const float ov = fsig(g[3]);
        c_own = fv * c_own + iv * gv;
        const float ho = ov * ftanh(c_own);
        if (act) hbuf[envloc][u] = ho;
        __builtin_amdgcn_wave_barrier();   // intra-wave LDS exchange; LDS is in-order per wave
#pragma unroll
        for (int k = 0; k < 25; ++k) h[k] = hbuf[envloc][k];
        float ov2 = lb;
#pragma unroll
        for (int k = 0; k < 25; ++k) ov2 += lw[k] * h[k];
        if (u < 2) out[b * 60 + t * 2 + u] = ov2;
    }
}

// ---------------- launch ----------------
extern "C" void kernel_launch(void* const* d_in, const int* in_sizes, int n_in,
                              void* d_out, int out_size, void* d_ws, size_t ws_size,
                              hipStream_t stream)
{
    const float* agent = (const float*)d_in[0];
    const float* av    = (const float*)d_in[1];
    const float* oth   = (const float*)d_in[2];
    const float* lane  = (const float*)d_in[3];
    const float* agWih = (const float*)d_in[4];
    const float* agWhh = (const float*)d_in[5];
    const float* agB   = (const float*)d_in[6];
    const float* avWih = (const float*)d_in[7];
    const float* avWhh = (const float*)d_in[8];
    const float* avB   = (const float*)d_in[9];
    const float* otWih = (const float*)d_in[10];
    const float* otWhh = (const float*)d_in[11];
    const float* otB   = (const float*)d_in[12];
    const float* deWih = (const float*)d_in[13];
    const float* deWhh = (const float*)d_in[14];
    const float* deB   = (const float*)d_in[15];
    const float* linW  = (const float*)d_in[16];
    const float* linB  = (const float*)d_in[17];
    const float* gavW  = (const float*)d_in[18];
    const float* gavAl = (const float*)d_in[19];
    const float* gavAr = (const float*)d_in[20];
    const float* gavB  = (const float*)d_in[21];
    const float* gotW  = (const float*)d_in[22];
    const float* gotAl = (const float*)d_in[23];
    const float* gotAr = (const float*)d_in[24];
    const float* gotB  = (const float*)d_in[25];
    const float* glnW  = (const float*)d_in[26];
    const float* glnAl = (const float*)d_in[27];
    const float* glnAr = (const float*)d_in[28];
    const float* glnB  = (const float*)d_in[29];
    // d_in[30]=others_dst, d_in[31]=lane_dst: implicit (i/16, i/32), not needed

    float* out = (float*)d_out;
    float* ws  = (float*)d_ws;

    enc_kernel<<<1600, 256, 0, stream>>>(agent, av, oth, lane,
                                         agWih, agWhh, agB,
                                         avWih, avWhh, avB,
                                         otWih, otWhh, otB, ws);

    gat_kernel<<<2048, 256, 0, stream>>>(ws,
                                         gavW, gavAl, gavAr, gavB,
                                         gotW, gotAl, gotAr, gotB,
                                         glnW, glnAl, glnAr, glnB,
                                         ws + 2611200, out + 122880);

    dec_kernel<<<256, 256, 0, stream>>>(ws, deWih, deWhh, deB, linW, linB, out);
}

// Round 11
// 152.310 us; speedup vs baseline: 2.6240x; 1.0015x over previous
//
#include <hip/hip_runtime.h>

// ---------------- constants ----------------
// B=2048, K_OTH=16, K_LANE=32, N_OTH=32768, N_LANE=65536
// node id ranges: [0,2048) agent | [2048,4096) av | [4096,36864) others | [36864,102400) lanes
// ws layout (floats): ag_h @0 | ag_c @51200 | av_c @102400 | ot_c @153600 | ln_c @972800 | env_code @2611200
// out layout: predict [2048*30*2] @0, env_lane_info [2048*25] @122880
//
// enc (MFMA): one wave (= one 64-thread block) owns 16 nodes for all 20 steps.
// Gates[112 packed rows][16 nodes] = 7 MFMA tiles (16x16x32 bf16);
// K layout: k<25 = h, k=25,26 = x0,x1, k=27 = 1.0 (bias), k>=28 = 0.
// Packed gate row p = 4u + r <-> torch row r*25 + u; lane (n=l&15, q=l>>4) C-frag
// holds gates r=0..3 of unit u=4T+q, node n (C layout col=lane&15, row=(lane>>4)*4+reg).
// fp32 precision via 3-term bf16 split: Ahi*Bhi + Ahi*Blo + Alo*Bhi.
// 64-thread blocks + __launch_bounds__(64,1): wave-granular VGPR alloc, cap 512 —
// r10 post-mortem: at cap 92 the ~130-reg working set was AGPR-juggled (~2x VALU issue).

typedef __attribute__((ext_vector_type(8))) short s16x8;
typedef __attribute__((ext_vector_type(4))) float fx4;

__device__ __forceinline__ float frcp(float x) { return __builtin_amdgcn_rcpf(x); }
__device__ __forceinline__ float fsig(float x) { return frcp(1.f + __expf(-x)); }
__device__ __forceinline__ float ftanh(float x) { return 1.f - 2.f * frcp(1.f + __expf(2.f * x)); }

__device__ __forceinline__ unsigned bfhi(float f) {          // RNE f32->bf16 (as u16)
    unsigned b = __float_as_uint(f);
    return (b + 0x7FFFu + ((b >> 16) & 1u)) >> 16;
}
__device__ __forceinline__ float bfval(unsigned h) { return __uint_as_float(h << 16); }
__device__ __forceinline__ unsigned packsplit(float f) {     // lo16 = bf16 hi part, hi16 = bf16 residual
    unsigned h = bfhi(f);
    unsigned l = bfhi(f - bfval(h));
    return h | (l << 16);
}

struct BF { s16x8 hi, lo; };
__device__ __forceinline__ BF buildB(const unsigned* L, int q, int n) {
    unsigned rb[8];
#pragma unroll
    for (int e = 0; e < 8; ++e) rb[e] = L[(8 * q + e) * 17 + n];
    union { unsigned w[4]; s16x8 v; } H, Lo;
#pragma unroll
    for (int i = 0; i < 4; ++i) {
        H.w[i]  = __builtin_amdgcn_perm(rb[2 * i + 1], rb[2 * i], 0x05040100u); // hi(k even)|hi(k odd)<<16
        Lo.w[i] = __builtin_amdgcn_perm(rb[2 * i + 1], rb[2 * i], 0x07060302u); // lo parts
    }
    BF r; r.hi = H.v; r.lo = Lo.v; return r;
}

__global__ __launch_bounds__(64, 1) void enc_kernel(
    const float* __restrict__ agent, const float* __restrict__ av,
    const float* __restrict__ oth,   const float* __restrict__ lane,
    const float* __restrict__ agWih, const float* __restrict__ agWhh, const float* __restrict__ agB,
    const float* __restrict__ avWih, const float* __restrict__ avWhh, const float* __restrict__ avB,
    const float* __restrict__ otWih, const float* __restrict__ otWhh, const float* __restrict__ otB,
    float* __restrict__ ws)
{
    __shared__ unsigned hlds[32 * 17];       // [k-slot 0..31][node 0..15], pad 17 words

    const int l   = threadIdx.x & 63;
    const int n   = l & 15;     // node within group (and A local row, B/D col)
    const int q   = l >> 4;     // k-block (and unit offset)
    unsigned* L = hlds;

    const int g0 = blockIdx.x;               // group id 0..6399 (16 nodes each)
    int task;
    if (g0 < 128) task = 0;
    else if (g0 < 256) task = 1;
    else if (g0 < 2304) task = 2;
    else task = 3;                           // lanes use the *agent* encoder (faithful to source bug)

    const float* Whh; const float* Wih; const float* Bp;
    if (task == 1)      { Wih = avWih; Whh = avWhh; Bp = avB; }
    else if (task == 2) { Wih = otWih; Whh = otWhh; Bp = otB; }
    else                { Wih = agWih; Whh = agWhh; Bp = agB; }

    const int node = g0 * 16 + n;
    const float* xp;
    if (task == 0)      xp = agent + node * 100;
    else if (task == 1) xp = av   + (node - 2048)  * 40;
    else if (task == 2) xp = oth  + (node - 4096)  * 40;
    else                xp = lane + (node - 36864) * 40;

    // preload this node's x for steps 5q..5q+4 (lane (n,q) is the step-owner)
    float xv[10];
#pragma unroll
    for (int s = 0; s < 5; ++s) {
        float2 t2 = *reinterpret_cast<const float2*>(xp + 2 * (5 * q + s));
        xv[2 * s] = t2.x; xv[2 * s + 1] = t2.y;
    }

    // ---- A fragments (weights, loop-invariant): 7 tiles x (hi,lo) ----
    s16x8 Ahi[7], Alo[7];
#pragma unroll
    for (int T = 0; T < 7; ++T) {
        const int p = 16 * T + n;            // packed gate row
        const int r = p & 3;
        const int u = p >> 2;
        int row = r * 25 + u;                // torch row
        if (row > 99) row = 99;              // clamp fake rows (u>=25) in-bounds
        float w[8];
        if (q < 3) {
            const float* src = Whh + row * 25 + 8 * q;
#pragma unroll
            for (int e = 0; e < 8; ++e) w[e] = src[e];
        } else {
            w[0] = Whh[row * 25 + 24];
            w[1] = Wih[row * 2];
            w[2] = Wih[row * 2 + 1];
            w[3] = Bp[row];
            w[4] = w[5] = w[6] = w[7] = 0.f;
        }
#pragma unroll
        for (int e = 0; e < 8; ++e) {
            unsigned h = bfhi(w[e]);
            unsigned lo = bfhi(w[e] - bfval(h));
            Ahi[T][e] = (short)h;
            Alo[T][e] = (short)lo;
        }
    }

    // ---- init LDS: h(=0) slots, x(0), bias-one, zero pads ----
#pragma unroll
    for (int T = 0; T < 6; ++T) L[(4 * T + q) * 17 + n] = 0u;
    if (q == 0) {
        L[24 * 17 + n] = 0u;
        L[25 * 17 + n] = packsplit(xv[0]);
        L[26 * 17 + n] = packsplit(xv[1]);
    }
    if (q == 3) L[27 * 17 + n] = 0x00003F80u;    // 1.0 (hi=0x3F80, lo=0)
    L[(28 + q) * 17 + n] = 0u;
    __builtin_amdgcn_wave_barrier();

    BF Bf = buildB(L, q, n);

    float c[7], hv[7];
#pragma unroll
    for (int T = 0; T < 7; ++T) { c[T] = 0.f; hv[T] = 0.f; }

    const fx4 zero4 = {0.f, 0.f, 0.f, 0.f};

#pragma unroll 1
    for (int tt = 0; tt < 4; ++tt) {
#pragma unroll
        for (int s = 0; s < 5; ++s) {
            // gates for all 16 nodes: 7 tiles x 3 split-terms
            fx4 acc[7];
#pragma unroll
            for (int T = 0; T < 7; ++T) {
                fx4 a = __builtin_amdgcn_mfma_f32_16x16x32_bf16(Ahi[T], Bf.hi, zero4, 0, 0, 0);
                a = __builtin_amdgcn_mfma_f32_16x16x32_bf16(Ahi[T], Bf.lo, a, 0, 0, 0);
                a = __builtin_amdgcn_mfma_f32_16x16x32_bf16(Alo[T], Bf.hi, a, 0, 0, 0);
                acc[T] = a;
            }
            // cell update: lane owns unit u=4T+q of node n; acc[T] = {i,f,g,o}
#pragma unroll
            for (int T = 0; T < 7; ++T) {
                const float iv = fsig(acc[T][0]);
                const float fv = fsig(acc[T][1]);
                const float gv = ftanh(acc[T][2]);
                const float ov = fsig(acc[T][3]);
                c[T]  = fv * c[T] + iv * gv;
                hv[T] = ov * ftanh(c[T]);
            }
            const bool lastStep = (tt == 3) && (s == 4);
            if (!lastStep) {
                // publish h(t): u = 4T+q for T<6, plus u=24 by q==0 (never touch x/bias slots 25..27)
#pragma unroll
                for (int T = 0; T < 6; ++T) L[(4 * T + q) * 17 + n] = packsplit(hv[T]);
                if (q == 0) L[24 * 17 + n] = packsplit(hv[6]);
                // publish x(t+1) by its owner lane
                if (s < 4) {
                    if (q == tt) {
                        L[25 * 17 + n] = packsplit(xv[2 * (s + 1)]);
                        L[26 * 17 + n] = packsplit(xv[2 * (s + 1) + 1]);
                    }
                } else {
                    if (q == tt + 1) {
                        L[25 * 17 + n] = packsplit(xv[0]);
                        L[26 * 17 + n] = packsplit(xv[1]);
                    }
                }
                __builtin_amdgcn_wave_barrier();
                Bf = buildB(L, q, n);
            }
        }
    }

    // ---- store c (and h for agents) ----
    float* dst_c; float* dst_h = nullptr;
    if (task == 0)      { dst_h = ws + node * 25; dst_c = ws + 51200 + node * 25; }
    else if (task == 1) dst_c = ws + 102400 + (node - 2048) * 25;
    else if (task == 2) dst_c = ws + 153600 + (node - 4096) * 25;
    else                dst_c = ws + 972800 + (node - 36864) * 25;
#pragma unroll
    for (int T = 0; T < 7; ++T) {
        const int u = 4 * T + q;
        if (u < 25) {
            dst_c[u] = c[T];
            if (task == 0) dst_h[u] = hv[T];
        }
    }
}

// ---------------- GAT + env_lane_info: one block per env ----------------
__global__ __launch_bounds__(256) void gat_kernel(
    const float* __restrict__ ws,
    const float* __restrict__ gavW, const float* __restrict__ gavAl, const float* __restrict__ gavAr, const float* __restrict__ gavB,
    const float* __restrict__ gotW, const float* __restrict__ gotAl, const float* __restrict__ gotAr, const float* __restrict__ gotB,
    const float* __restrict__ glnW, const float* __restrict__ glnAl, const float* __restrict__ glnAr, const float* __restrict__ glnB,
    float* __restrict__ envcode, float* __restrict__ lane_out)
{
    __shared__ float X[50 * 25];   // 0: ag_c, 1: av_c, 2..17: ot srcs, 18..49: ln srcs
    __shared__ float F[52 * 25];   // 0: fs_av, 1: fd_av(unused), 2: fd_ot, 3: fd_ln, 4..19: fs_ot, 20..51: fs_ln
    __shared__ float er[10];       // [conv(ot=0,ln=1)][head]
    __shared__ float Eo[16 * 5];
    __shared__ float El[32 * 5];

    const int tid = threadIdx.x;
    const int b = blockIdx.x;
    const float* agc = ws + 51200;
    const float* avc = ws + 102400;
    const float* otc = ws + 153600;
    const float* lnc = ws + 972800;

    for (int i = tid; i < 1250; i += 256) {
        int r = i / 25, k = i - r * 25;
        float v;
        if (r == 0)      v = agc[b * 25 + k];
        else if (r == 1) v = avc[b * 25 + k];
        else if (r < 18) v = otc[(b * 16 + (r - 2)) * 25 + k];
        else             v = lnc[(b * 32 + (r - 18)) * 25 + k];
        X[i] = v;
    }
    __syncthreads();

    for (int d = tid; d < 1300; d += 256) {
        int row = d / 25, o = d - row * 25;
        const float* W; const float* xs;
        if (row == 0)      { W = gavW; xs = &X[1 * 25]; }
        else if (row == 1) { W = gavW; xs = &X[0]; }
        else if (row == 2) { W = gotW; xs = &X[0]; }
        else if (row == 3) { W = glnW; xs = &X[0]; }
        else if (row < 20) { W = gotW; xs = &X[(2 + row - 4) * 25]; }
        else               { W = glnW; xs = &X[(18 + row - 20) * 25]; }
        float acc = 0.f;
#pragma unroll
        for (int k = 0; k < 25; ++k) acc += W[o * 25 + k] * xs[k];
        F[row * 25 + o] = acc;
    }
    __syncthreads();

    if (tid < 10) {
        int conv = tid / 5, nn = tid - conv * 5;
        const float* ar = conv ? glnAr : gotAr;
        const float* fd = &F[(2 + conv) * 25];
        float acc = 0.f;
#pragma unroll
        for (int f = 0; f < 5; ++f) acc += fd[nn * 5 + f] * ar[nn * 5 + f];
        er[tid] = acc;
    }
    __syncthreads();

    for (int d = tid; d < 240; d += 256) {
        if (d < 80) {
            int i = d / 5, nn = d - i * 5;
            const float* fsrow = &F[(4 + i) * 25];
            float acc = er[nn];
#pragma unroll
            for (int f = 0; f < 5; ++f) acc += fsrow[nn * 5 + f] * gotAl[nn * 5 + f];
            Eo[d] = (acc > 0.f) ? acc : 0.2f * acc;
        } else {
            int d2 = d - 80;
            int i = d2 / 5, nn = d2 - i * 5;
            const float* fsrow = &F[(20 + i) * 25];
            float acc = er[5 + nn];
#pragma unroll
            for (int f = 0; f < 5; ++f) acc += fsrow[nn * 5 + f] * glnAl[nn * 5 + f];
            El[d2] = (acc > 0.f) ? acc : 0.2f * acc;
        }
    }
    __syncthreads();

    if (tid < 10) {
        int conv = tid / 5, nn = tid - conv * 5;
        if (conv == 0) {
            float m = -1e30f;
            for (int i = 0; i < 16; ++i) m = fmaxf(m, Eo[i * 5 + nn]);
            float s = 0.f;
            for (int i = 0; i < 16; ++i) s += __expf(Eo[i * 5 + nn] - m);
            float inv = frcp(s);
            for (int i = 0; i < 16; ++i) Eo[i * 5 + nn] = __expf(Eo[i * 5 + nn] - m) * inv;
        } else {
            float m = -1e30f;
            for (int i = 0; i < 32; ++i) m = fmaxf(m, El[i * 5 + nn]);
            float s = 0.f;
            for (int i = 0; i < 32; ++i) s += __expf(El[i * 5 + nn] - m);
            float inv = frcp(s);
            for (int i = 0; i < 32; ++i) El[i * 5 + nn] = __expf(El[i * 5 + nn] - m) * inv;
        }
    }
    __syncthreads();

    if (tid < 25) {
        const int o = tid, nn = o / 5;
        float v_av = F[o] + gavB[o];
        float s = 0.f;
        for (int i = 0; i < 16; ++i) s += Eo[i * 5 + nn] * F[(4 + i) * 25 + o];
        float v_ot = s + gotB[o];
        s = 0.f;
        for (int i = 0; i < 32; ++i) s += El[i * 5 + nn] * F[(20 + i) * 25 + o];
        float v_ln = s + glnB[o];
        envcode[b * 25 + o] = (v_av + v_ot + v_ln) * (1.f / 3.f);
        float m = 0.f;
        for (int i = 0; i < 32; ++i) m += X[(18 + i) * 25 + o];
        lane_out[b * 25 + o] = m * (1.f / 32.f);
    }
}

// ---------------- decoder: 25 lanes per env, 2 envs per wave, reg weights ----------------
__global__ __launch_bounds__(256) void dec_kernel(
    const float* __restrict__ ws,
    const float* __restrict__ deWih, const float* __restrict__ deWhh, const float* __restrict__ deB,
    const float* __restrict__ linW,  const float* __restrict__ linB,
    float* __restrict__ out)
{
    __shared__ float hbuf[8][28];
    const int tid  = threadIdx.x;
    const int lane = tid & 63;
    const int half = lane >> 5;
    const int u    = lane & 31;
    const int u2   = (u < 25) ? u : 0;
    const bool act = (u < 25);
    const int wglob = (blockIdx.x * 256 + tid) >> 6;
    const int b = wglob * 2 + half;                 // env id
    const int envloc = ((tid >> 6) << 1) + half;    // 0..7 within block

    float U[4][25], Wi[4], Bb[4];
#pragma unroll
    for (int r = 0; r < 4; ++r) {
        const int row = u2 + 25 * r;
#pragma unroll
        for (int k = 0; k < 25; ++k) U[r][k] = deWhh[row * 25 + k];
        Wi[r] = deWih[row];
        Bb[r] = deB[row];
    }
    const int j = u & 1;
    float lw[25];
#pragma unroll
    for (int k = 0; k < 25; ++k) lw[k] = linW[j * 25 + k];
    const float lb = linB[j];

    const float* agh = ws;
    const float* agc = ws + 51200;
    const float* env = ws + 2611200;

    float h[25];
#pragma unroll
    for (int k = 0; k < 25; ++k) h[k] = agh[b * 25 + k];
    float c_own = agc[b * 25 + u2] + env[b * 25 + u2];

    for (int t = 0; t < 30; ++t) {
        const float tt = 0.1f * (float)t;
        float g[4];
#pragma unroll
        for (int r = 0; r < 4; ++r) {
            float acc = Bb[r] + Wi[r] * tt;
#pragma unroll
            for (int k = 0; k < 25; ++k) acc += U[r][k] * h[k];
            g[r] = acc;
        }
        const float iv = fsig(g[0]);
        const float fv = fsig(g[1]);
        const float gv = ftanh(g[2]);
        const float ov = fsig(g[3]);
        c_own = fv * c_own + iv * gv;
        const float ho = ov * ftanh(c_own);
        if (act) hbuf[envloc][u] = ho;
        __builtin_amdgcn_wave_barrier();   // intra-wave LDS exchange; LDS is in-order per wave
#pragma unroll
        for (int k = 0; k < 25; ++k) h[k] = hbuf[envloc][k];
        float ov2 = lb;
#pragma unroll
        for (int k = 0; k < 25; ++k) ov2 += lw[k] * h[k];
        if (u < 2) out[b * 60 + t * 2 + u] = ov2;
    }
}

// ---------------- launch ----------------
extern "C" void kernel_launch(void* const* d_in, const int* in_sizes, int n_in,
                              void* d_out, int out_size, void* d_ws, size_t ws_size,
                              hipStream_t stream)
{
    const float* agent = (const float*)d_in[0];
    const float* av    = (const float*)d_in[1];
    const float* oth   = (const float*)d_in[2];
    const float* lane  = (const float*)d_in[3];
    const float* agWih = (const float*)d_in[4];
    const float* agWhh = (const float*)d_in[5];
    const float* agB   = (const float*)d_in[6];
    const float* avWih = (const float*)d_in[7];
    const float* avWhh = (const float*)d_in[8];
    const float* avB   = (const float*)d_in[9];
    const float* otWih = (const float*)d_in[10];
    const float* otWhh = (const float*)d_in[11];
    const float* otB   = (const float*)d_in[12];
    const float* deWih = (const float*)d_in[13];
    const float* deWhh = (const float*)d_in[14];
    const float* deB   = (const float*)d_in[15];
    const float* linW  = (const float*)d_in[16];
    const float* linB  = (const float*)d_in[17];
    const float* gavW  = (const float*)d_in[18];
    const float* gavAl = (const float*)d_in[19];
    const float* gavAr = (const float*)d_in[20];
    const float* gavB  = (const float*)d_in[21];
    const float* gotW  = (const float*)d_in[22];
    const float* gotAl = (const float*)d_in[23];
    const float* gotAr = (const float*)d_in[24];
    const float* gotB  = (const float*)d_in[25];
    const float* glnW  = (const float*)d_in[26];
    const float* glnAl = (const float*)d_in[27];
    const float* glnAr = (const float*)d_in[28];
    const float* glnB  = (const float*)d_in[29];
    // d_in[30]=others_dst, d_in[31]=lane_dst: implicit (i/16, i/32), not needed

    float* out = (float*)d_out;
    float* ws  = (float*)d_ws;

    enc_kernel<<<6400, 64, 0, stream>>>(agent, av, oth, lane,
                                        agWih, agWhh, agB,
                                        avWih, avWhh, avB,
                                        otWih, otWhh, otB, ws);

    gat_kernel<<<2048, 256, 0, stream>>>(ws,
                                         gavW, gavAl, gavAr, gavB,
                                         gotW, gotAl, gotAr, gotB,
                                         glnW, glnAl, glnAr, glnB,
                                         ws + 2611200, out + 122880);

    dec_kernel<<<256, 256, 0, stream>>>(ws, deWih, deWhh, deB, linW, linB, out);
}

// Round 12
// 143.333 us; speedup vs baseline: 2.7883x; 1.0626x over previous
//
#include <hip/hip_runtime.h>

// ---------------- constants ----------------
// B=2048, K_OTH=16, K_LANE=32, N_OTH=32768, N_LANE=65536
// node id ranges: [0,2048) agent | [2048,4096) av | [4096,36864) others | [36864,102400) lanes
// ws layout (floats): ag_h @0 | ag_c @51200 | av_c @102400 | ot_c @153600 | ln_c @972800 | env_code @2611200
// out layout: predict [2048*30*2] @0, env_lane_info [2048*25] @122880
//
// enc (MFMA): one wave owns TWO 16-node groups (A: g=2b, B: g=2b+1) for all 20 steps.
// Per group: Gates[112 packed rows][16 nodes] = 7 MFMA tiles (16x16x32 bf16).
// K layout: k<25 = h, k=25,26 = x0,x1, k=27 = 1.0 (bias), k>=28 = 0.
// Packed gate row p = 4u + r <-> torch row r*25 + u; lane (n=l&15,q=l>>4) C-frag holds
// gates r=0..3 of unit u=4T+q, node n (C layout col=lane&15, row=(lane>>4)*4+reg).
// h/x live in LDS as fp32 (cheap writes); bf16 hi/lo built on READ via v_cvt_pk_bf16_f32.
// Gate weights pre-scaled by log2e (i,f,o) / 2*log2e (g) -> activations use raw v_exp_f32 (2^x).
// fp32 precision via 3-term bf16 split: Ahi*Bhi + Ahi*Blo + Alo*Bhi.

typedef __attribute__((ext_vector_type(8))) short s16x8;
typedef __attribute__((ext_vector_type(4))) float fx4;

__device__ __forceinline__ float frcp(float x) { return __builtin_amdgcn_rcpf(x); }
__device__ __forceinline__ float fsig(float x) { return frcp(1.f + __expf(-x)); }
__device__ __forceinline__ float ftanh(float x) { return 1.f - 2.f * frcp(1.f + __expf(2.f * x)); }

__device__ __forceinline__ float exp2p(float x) { float r; asm("v_exp_f32 %0, %1"  : "=v"(r) : "v"(x)); return r; }   // 2^x
__device__ __forceinline__ float exp2m(float x) { float r; asm("v_exp_f32 %0, -%1" : "=v"(r) : "v"(x)); return r; }   // 2^-x
// gp = log2e * g  ->  sigmoid(g)
__device__ __forceinline__ float sigE(float gp)  { return frcp(1.f + exp2m(gp)); }
// gp = 2*log2e * g ->  tanh(g)
__device__ __forceinline__ float tanhE(float gp) { return 1.f - 2.f * frcp(1.f + exp2p(gp)); }

__device__ __forceinline__ unsigned bfhi(float f) {          // RNE f32->bf16 (as u16)
    unsigned b = __float_as_uint(f);
    return (b + 0x7FFFu + ((b >> 16) & 1u)) >> 16;
}
__device__ __forceinline__ float bfval(unsigned h) { return __uint_as_float(h << 16); }

// read 8 fp32 k-elements from LDS, produce bf16 hi + residual-lo fragments
__device__ __forceinline__ void buildB2(const float* L, int q, int n, s16x8& hi, s16x8& lo) {
    float f[8];
#pragma unroll
    for (int e = 0; e < 8; ++e) f[e] = L[(8 * q + e) * 17 + n];   // pairs fuse to ds_read2_b32
    union { unsigned w[4]; s16x8 v; } H, Lo;
#pragma unroll
    for (int i = 0; i < 4; ++i) {
        unsigned hw;
        asm("v_cvt_pk_bf16_f32 %0, %1, %2" : "=v"(hw) : "v"(f[2 * i]), "v"(f[2 * i + 1]));
        const float r0 = f[2 * i]     - __uint_as_float(hw << 16);
        const float r1 = f[2 * i + 1] - __uint_as_float(hw & 0xFFFF0000u);
        unsigned lw;
        asm("v_cvt_pk_bf16_f32 %0, %1, %2" : "=v"(lw) : "v"(r0), "v"(r1));
        H.w[i] = hw; Lo.w[i] = lw;
    }
    hi = H.v; lo = Lo.v;
}

__global__ __launch_bounds__(64, 1) void enc_kernel(
    const float* __restrict__ agent, const float* __restrict__ av,
    const float* __restrict__ oth,   const float* __restrict__ lane,
    const float* __restrict__ agWih, const float* __restrict__ agWhh, const float* __restrict__ agB,
    const float* __restrict__ avWih, const float* __restrict__ avWhh, const float* __restrict__ avB,
    const float* __restrict__ otWih, const float* __restrict__ otWhh, const float* __restrict__ otB,
    float* __restrict__ ws)
{
    __shared__ float hlds[2][32 * 17];       // [group][k-slot 0..31][node 0..15], pad 17 words

    const int l = threadIdx.x & 63;
    const int n = l & 15;     // node within group (and A local row, B/D col)
    const int q = l >> 4;     // k-block (and unit offset)
    float* LA = hlds[0];
    float* LB = hlds[1];

    const int gA = blockIdx.x * 2;           // groups gA, gA+1 (task boundaries 128/256/2304 all even)
    int task;
    if (gA < 128) task = 0;
    else if (gA < 256) task = 1;
    else if (gA < 2304) task = 2;
    else task = 3;                           // lanes use the *agent* encoder (faithful to source bug)

    const float* Whh; const float* Wih; const float* Bp;
    if (task == 1)      { Wih = avWih; Whh = avWhh; Bp = avB; }
    else if (task == 2) { Wih = otWih; Whh = otWhh; Bp = otB; }
    else                { Wih = agWih; Whh = agWhh; Bp = agB; }

    const int nodeA = gA * 16 + n;
    const int nodeB = nodeA + 16;
    const float* xpA; const float* xpB;
    if (task == 0)      { xpA = agent + nodeA * 100;          xpB = agent + nodeB * 100; }
    else if (task == 1) { xpA = av + (nodeA - 2048) * 40;     xpB = av + (nodeB - 2048) * 40; }
    else if (task == 2) { xpA = oth + (nodeA - 4096) * 40;    xpB = oth + (nodeB - 4096) * 40; }
    else                { xpA = lane + (nodeA - 36864) * 40;  xpB = lane + (nodeB - 36864) * 40; }

    // preload x for steps 5q..5q+4 (lane (n,q) is the step-owner)
    float xvA[10], xvB[10];
#pragma unroll
    for (int s = 0; s < 5; ++s) {
        float2 a2 = *reinterpret_cast<const float2*>(xpA + 2 * (5 * q + s));
        float2 b2 = *reinterpret_cast<const float2*>(xpB + 2 * (5 * q + s));
        xvA[2 * s] = a2.x; xvA[2 * s + 1] = a2.y;
        xvB[2 * s] = b2.x; xvB[2 * s + 1] = b2.y;
    }

    // ---- A fragments (weights, loop-invariant, shared by both groups): 7 tiles x (hi,lo) ----
    const float L2E = 1.4426950408889634f;
    s16x8 Ahi[7], Alo[7];
#pragma unroll
    for (int T = 0; T < 7; ++T) {
        const int p = 16 * T + n;            // packed gate row
        const int r = p & 3;
        const int u = p >> 2;
        int row = r * 25 + u;                // torch row
        if (row > 99) row = 99;              // clamp fake rows (u>=25) in-bounds
        const float sc = (r == 2) ? 2.f * L2E : L2E;   // fold log2e (2x for tanh gate)
        float w[8];
        if (q < 3) {
            const float* src = Whh + row * 25 + 8 * q;
#pragma unroll
            for (int e = 0; e < 8; ++e) w[e] = src[e] * sc;
        } else {
            w[0] = Whh[row * 25 + 24] * sc;
            w[1] = Wih[row * 2] * sc;
            w[2] = Wih[row * 2 + 1] * sc;
            w[3] = Bp[row] * sc;
            w[4] = w[5] = w[6] = w[7] = 0.f;
        }
#pragma unroll
        for (int e = 0; e < 8; ++e) {
            unsigned h = bfhi(w[e]);
            unsigned lo = bfhi(w[e] - bfval(h));
            Ahi[T][e] = (short)h;
            Alo[T][e] = (short)lo;
        }
    }

    // ---- init LDS: h(=0) slots, x(0), bias-one, zero pads ----
#pragma unroll
    for (int T = 0; T < 6; ++T) { LA[(4 * T + q) * 17 + n] = 0.f; LB[(4 * T + q) * 17 + n] = 0.f; }
    if (q == 0) {
        LA[24 * 17 + n] = 0.f;        LB[24 * 17 + n] = 0.f;
        LA[25 * 17 + n] = xvA[0];     LB[25 * 17 + n] = xvB[0];
        LA[26 * 17 + n] = xvA[1];     LB[26 * 17 + n] = xvB[1];
    }
    if (q == 3) { LA[27 * 17 + n] = 1.f; LB[27 * 17 + n] = 1.f; }
    LA[(28 + q) * 17 + n] = 0.f; LB[(28 + q) * 17 + n] = 0.f;
    __builtin_amdgcn_wave_barrier();

    s16x8 BhA, BlA, BhB, BlB;
    buildB2(LA, q, n, BhA, BlA);
    buildB2(LB, q, n, BhB, BlB);

    float cA[7], hA[7], cB[7], hB[7];
#pragma unroll
    for (int T = 0; T < 7; ++T) { cA[T] = 0.f; hA[T] = 0.f; cB[T] = 0.f; hB[T] = 0.f; }

    const fx4 zero4 = {0.f, 0.f, 0.f, 0.f};
    const float TL2E = 2.f * L2E;

#pragma unroll 1
    for (int tt = 0; tt < 4; ++tt) {
#pragma unroll
        for (int s = 0; s < 5; ++s) {
            fx4 accA[7], accB[7];
#pragma unroll
            for (int T = 0; T < 7; ++T) {
                fx4 a = __builtin_amdgcn_mfma_f32_16x16x32_bf16(Ahi[T], BhA, zero4, 0, 0, 0);
                a = __builtin_amdgcn_mfma_f32_16x16x32_bf16(Ahi[T], BlA, a, 0, 0, 0);
                accA[T] = __builtin_amdgcn_mfma_f32_16x16x32_bf16(Alo[T], BhA, a, 0, 0, 0);
                fx4 b = __builtin_amdgcn_mfma_f32_16x16x32_bf16(Ahi[T], BhB, zero4, 0, 0, 0);
                b = __builtin_amdgcn_mfma_f32_16x16x32_bf16(Ahi[T], BlB, b, 0, 0, 0);
                accB[T] = __builtin_amdgcn_mfma_f32_16x16x32_bf16(Alo[T], BhB, b, 0, 0, 0);
            }
            // cell update: lane owns unit u=4T+q of node n; acc[T] = {i,f,g,o} (pre-scaled by log2e)
#pragma unroll
            for (int T = 0; T < 7; ++T) {
                const float iv = sigE(accA[T][0]);
                const float fv = sigE(accA[T][1]);
                const float gv = tanhE(accA[T][2]);
                const float ov = sigE(accA[T][3]);
                cA[T] = fv * cA[T] + iv * gv;
                hA[T] = ov * tanhE(cA[T] * TL2E);
            }
#pragma unroll
            for (int T = 0; T < 7; ++T) {
                const float iv = sigE(accB[T][0]);
                const float fv = sigE(accB[T][1]);
                const float gv = tanhE(accB[T][2]);
                const float ov = sigE(accB[T][3]);
                cB[T] = fv * cB[T] + iv * gv;
                hB[T] = ov * tanhE(cB[T] * TL2E);
            }
            const bool lastStep = (tt == 3) && (s == 4);
            if (!lastStep) {
                // publish h(t+1) as fp32 (no conversion): k=4T+q for T<6, k=24 by q==0
#pragma unroll
                for (int T = 0; T < 6; ++T) {
                    LA[(4 * T + q) * 17 + n] = hA[T];
                    LB[(4 * T + q) * 17 + n] = hB[T];
                }
                if (q == 0) { LA[24 * 17 + n] = hA[6]; LB[24 * 17 + n] = hB[6]; }
                // publish x(t+1) by its owner lane
                if (s < 4) {
                    if (q == tt) {
                        LA[25 * 17 + n] = xvA[2 * (s + 1)]; LA[26 * 17 + n] = xvA[2 * (s + 1) + 1];
                        LB[25 * 17 + n] = xvB[2 * (s + 1)]; LB[26 * 17 + n] = xvB[2 * (s + 1) + 1];
                    }
                } else {
                    if (q == tt + 1) {
                        LA[25 * 17 + n] = xvA[0]; LA[26 * 17 + n] = xvA[1];
                        LB[25 * 17 + n] = xvB[0]; LB[26 * 17 + n] = xvB[1];
                    }
                }
                __builtin_amdgcn_wave_barrier();
                buildB2(LA, q, n, BhA, BlA);
                buildB2(LB, q, n, BhB, BlB);
            }
        }
    }

    // ---- store c (and h for agents) ----
    float* dstcA; float* dsthA = nullptr;
    float* dstcB; float* dsthB = nullptr;
    if (task == 0)      { dsthA = ws + nodeA * 25; dstcA = ws + 51200 + nodeA * 25;
                          dsthB = ws + nodeB * 25; dstcB = ws + 51200 + nodeB * 25; }
    else if (task == 1) { dstcA = ws + 102400 + (nodeA - 2048) * 25;  dstcB = ws + 102400 + (nodeB - 2048) * 25; }
    else if (task == 2) { dstcA = ws + 153600 + (nodeA - 4096) * 25;  dstcB = ws + 153600 + (nodeB - 4096) * 25; }
    else                { dstcA = ws + 972800 + (nodeA - 36864) * 25; dstcB = ws + 972800 + (nodeB - 36864) * 25; }
#pragma unroll
    for (int T = 0; T < 7; ++T) {
        const int u = 4 * T + q;
        if (u < 25) {
            dstcA[u] = cA[T];
            dstcB[u] = cB[T];
            if (task == 0) { dsthA[u] = hA[T]; dsthB[u] = hB[T]; }
        }
    }
}

// ---------------- GAT + env_lane_info: one block per env ----------------
__global__ __launch_bounds__(256) void gat_kernel(
    const float* __restrict__ ws,
    const float* __restrict__ gavW, const float* __restrict__ gavAl, const float* __restrict__ gavAr, const float* __restrict__ gavB,
    const float* __restrict__ gotW, const float* __restrict__ gotAl, const float* __restrict__ gotAr, const float* __restrict__ gotB,
    const float* __restrict__ glnW, const float* __restrict__ glnAl, const float* __restrict__ glnAr, const float* __restrict__ glnB,
    float* __restrict__ envcode, float* __restrict__ lane_out)
{
    __shared__ float X[50 * 25];   // 0: ag_c, 1: av_c, 2..17: ot srcs, 18..49: ln srcs
    __shared__ float F[52 * 25];   // 0: fs_av, 1: fd_av(unused), 2: fd_ot, 3: fd_ln, 4..19: fs_ot, 20..51: fs_ln
    __shared__ float er[10];       // [conv(ot=0,ln=1)][head]
    __shared__ float Eo[16 * 5];
    __shared__ float El[32 * 5];

    const int tid = threadIdx.x;
    const int b = blockIdx.x;
    const float* agc = ws + 51200;
    const float* avc = ws + 102400;
    const float* otc = ws + 153600;
    const float* lnc = ws + 972800;

    for (int i = tid; i < 1250; i += 256) {
        int r = i / 25, k = i - r * 25;
        float v;
        if (r == 0)      v = agc[b * 25 + k];
        else if (r == 1) v = avc[b * 25 + k];
        else if (r < 18) v = otc[(b * 16 + (r - 2)) * 25 + k];
        else             v = lnc[(b * 32 + (r - 18)) * 25 + k];
        X[i] = v;
    }
    __syncthreads();

    for (int d = tid; d < 1300; d += 256) {
        int row = d / 25, o = d - row * 25;
        const float* W; const float* xs;
        if (row == 0)      { W = gavW; xs = &X[1 * 25]; }
        else if (row == 1) { W = gavW; xs = &X[0]; }
        else if (row == 2) { W = gotW; xs = &X[0]; }
        else if (row == 3) { W = glnW; xs = &X[0]; }
        else if (row < 20) { W = gotW; xs = &X[(2 + row - 4) * 25]; }
        else               { W = glnW; xs = &X[(18 + row - 20) * 25]; }
        float acc = 0.f;
#pragma unroll
        for (int k = 0; k < 25; ++k) acc += W[o * 25 + k] * xs[k];
        F[row * 25 + o] = acc;
    }
    __syncthreads();

    if (tid < 10) {
        int conv = tid / 5, nn = tid - conv * 5;
        const float* ar = conv ? glnAr : gotAr;
        const float* fd = &F[(2 + conv) * 25];
        float acc = 0.f;
#pragma unroll
        for (int f = 0; f < 5; ++f) acc += fd[nn * 5 + f] * ar[nn * 5 + f];
        er[tid] = acc;
    }
    __syncthreads();

    for (int d = tid; d < 240; d += 256) {
        if (d < 80) {
            int i = d / 5, nn = d - i * 5;
            const float* fsrow = &F[(4 + i) * 25];
            float acc = er[nn];
#pragma unroll
            for (int f = 0; f < 5; ++f) acc += fsrow[nn * 5 + f] * gotAl[nn * 5 + f];
            Eo[d] = (acc > 0.f) ? acc : 0.2f * acc;
        } else {
            int d2 = d - 80;
            int i = d2 / 5, nn = d2 - i * 5;
            const float* fsrow = &F[(20 + i) * 25];
            float acc = er[5 + nn];
#pragma unroll
            for (int f = 0; f < 5; ++f) acc += fsrow[nn * 5 + f] * glnAl[nn * 5 + f];
            El[d2] = (acc > 0.f) ? acc : 0.2f * acc;
        }
    }
    __syncthreads();

    if (tid < 10) {
        int conv = tid / 5, nn = tid - conv * 5;
        if (conv == 0) {
            float m = -1e30f;
            for (int i = 0; i < 16; ++i) m = fmaxf(m, Eo[i * 5 + nn]);
            float s = 0.f;
            for (int i = 0; i < 16; ++i) s += __expf(Eo[i * 5 + nn] - m);
            float inv = frcp(s);
            for (int i = 0; i < 16; ++i) Eo[i * 5 + nn] = __expf(Eo[i * 5 + nn] - m) * inv;
        } else {
            float m = -1e30f;
            for (int i = 0; i < 32; ++i) m = fmaxf(m, El[i * 5 + nn]);
            float s = 0.f;
            for (int i = 0; i < 32; ++i) s += __expf(El[i * 5 + nn] - m);
            float inv = frcp(s);
            for (int i = 0; i < 32; ++i) El[i * 5 + nn] = __expf(El[i * 5 + nn] - m) * inv;
        }
    }
    __syncthreads();

    if (tid < 25) {
        const int o = tid, nn = o / 5;
        float v_av = F[o] + gavB[o];
        float s = 0.f;
        for (int i = 0; i < 16; ++i) s += Eo[i * 5 + nn] * F[(4 + i) * 25 + o];
        float v_ot = s + gotB[o];
        s = 0.f;
        for (int i = 0; i < 32; ++i) s += El[i * 5 + nn] * F[(20 + i) * 25 + o];
        float v_ln = s + glnB[o];
        envcode[b * 25 + o] = (v_av + v_ot + v_ln) * (1.f / 3.f);
        float m = 0.f;
        for (int i = 0; i < 32; ++i) m += X[(18 + i) * 25 + o];
        lane_out[b * 25 + o] = m * (1.f / 32.f);
    }
}

// ---------------- decoder: 25 lanes per env, 2 envs per wave, reg weights ----------------
__global__ __launch_bounds__(256) void dec_kernel(
    const float* __restrict__ ws,
    const float* __restrict__ deWih, const float* __restrict__ deWhh, const float* __restrict__ deB,
    const float* __restrict__ linW,  const float* __restrict__ linB,
    float* __restrict__ out)
{
    __shared__ float hbuf[8][28];
    const int tid  = threadIdx.x;
    const int lane = tid & 63;
    const int half = lane >> 5;
    const int u    = lane & 31;
    const int u2   = (u < 25) ? u : 0;
    const bool act = (u < 25);
    const int wglob = (blockIdx.x * 256 + tid) >> 6;
    const int b = wglob * 2 + half;                 // env id
    const int envloc = ((tid >> 6) << 1) + half;    // 0..7 within block

    float U[4][25], Wi[4], Bb[4];
#pragma unroll
    for (int r = 0; r < 4; ++r) {
        const int row = u2 + 25 * r;
#pragma unroll
        for (int k = 0; k < 25; ++k) U[r][k] = deWhh[row * 25 + k];
        Wi[r] = deWih[row];
        Bb[r] = deB[row];
    }
    const int j = u & 1;
    float lw[25];
#pragma unroll
    for (int k = 0; k < 25; ++k) lw[k] = linW[j * 25 + k];
    const float lb = linB[j];

    const float* agh = ws;
    const float* agc = ws + 51200;
    const float* env = ws + 2611200;

    float h[25];
#pragma unroll
    for (int k = 0; k < 25; ++k) h[k] = agh[b * 25 + k];
    float c_own = agc[b * 25 + u2] + env[b * 25 + u2];

    for (int t = 0; t < 30; ++t) {
        const float tt = 0.1f * (float)t;
        float g[4];
#pragma unroll
        for (int r = 0; r < 4; ++r) {
            float acc = Bb[r] + Wi[r] * tt;
#pragma unroll
            for (int k = 0; k < 25; ++k) acc += U[r][k] * h[k];
            g[r] = acc;
        }
        const float iv = fsig(g[0]);
        const float fv = fsig(g[1]);
        const float gv = ftanh(g[2]);
        const float ov = fsig(g[3]);
        c_own = fv * c_own + iv * gv;
        const float ho = ov * ftanh(c_own);
        if (act) hbuf[envloc][u] = ho;
        __builtin_amdgcn_wave_barrier();   // intra-wave LDS exchange; LDS is in-order per wave
#pragma unroll
        for (int k = 0; k < 25; ++k) h[k] = hbuf[envloc][k];
        float ov2 = lb;
#pragma unroll
        for (int k = 0; k < 25; ++k) ov2 += lw[k] * h[k];
        if (u < 2) out[b * 60 + t * 2 + u] = ov2;
    }
}

// ---------------- launch ----------------
extern "C" void kernel_launch(void* const* d_in, const int* in_sizes, int n_in,
                              void* d_out, int out_size, void* d_ws, size_t ws_size,
                              hipStream_t stream)
{
    const float* agent = (const float*)d_in[0];
    const float* av    = (const float*)d_in[1];
    const float* oth   = (const float*)d_in[2];
    const float* lane  = (const float*)d_in[3];
    const float* agWih = (const float*)d_in[4];
    const float* agWhh = (const float*)d_in[5];
    const float* agB   = (const float*)d_in[6];
    const float* avWih = (const float*)d_in[7];
    const float* avWhh = (const float*)d_in[8];
    const float* avB   = (const float*)d_in[9];
    const float* otWih = (const float*)d_in[10];
    const float* otWhh = (const float*)d_in[11];
    const float* otB   = (const float*)d_in[12];
    const float* deWih = (const float*)d_in[13];
    const float* deWhh = (const float*)d_in[14];
    const float* deB   = (const float*)d_in[15];
    const float* linW  = (const float*)d_in[16];
    const float* linB  = (const float*)d_in[17];
    const float* gavW  = (const float*)d_in[18];
    const float* gavAl = (const float*)d_in[19];
    const float* gavAr = (const float*)d_in[20];
    const float* gavB  = (const float*)d_in[21];
    const float* gotW  = (const float*)d_in[22];
    const float* gotAl = (const float*)d_in[23];
    const float* gotAr = (const float*)d_in[24];
    const float* gotB  = (const float*)d_in[25];
    const float* glnW  = (const float*)d_in[26];
    const float* glnAl = (const float*)d_in[27];
    const float* glnAr = (const float*)d_in[28];
    const float* glnB  = (const float*)d_in[29];
    // d_in[30]=others_dst, d_in[31]=lane_dst: implicit (i/16, i/32), not needed

    float* out = (float*)d_out;
    float* ws  = (float*)d_ws;

    enc_kernel<<<3200, 64, 0, stream>>>(agent, av, oth, lane,
                                        agWih, agWhh, agB,
                                        avWih, avWhh, avB,
                                        otWih, otWhh, otB, ws);

    gat_kernel<<<2048, 256, 0, stream>>>(ws,
                                         gavW, gavAl, gavAr, gavB,
                                         gotW, gotAl, gotAr, gotB,
                                         glnW, glnAl, glnAr, glnB,
                                         ws + 2611200, out + 122880);

    dec_kernel<<<256, 256, 0, stream>>>(ws, deWih, deWhh, deB, linW, linB, out);
}

// Round 13
// 133.099 us; speedup vs baseline: 3.0027x; 1.0769x over previous
//
#include <hip/hip_runtime.h>

// ---------------- constants ----------------
// B=2048, K_OTH=16, K_LANE=32, N_OTH=32768, N_LANE=65536
// node id ranges: [0,2048) agent | [2048,4096) av | [4096,36864) others | [36864,102400) lanes
// ws layout (floats): ag_h @0 | ag_c @51200 | av_c @102400 | ot_c @153600 | ln_c @972800 | env_code @2611200
// out layout: predict [2048*30*2] @0, env_lane_info [2048*25] @122880
//
// enc (MFMA): one wave (64-thr block) owns ONE 16-node group for all 20 steps.
// Gates[112 packed rows][16 nodes] = 7 MFMA tiles (16x16x32 bf16).
// K layout: k<25 = h, k=25,26 = x0,x1, k=27 = 1.0 (bias), k>=28 = 0.
// Packed gate row p = 4u + r <-> torch row r*25 + u; lane (n=l&15,q=l>>4) C-frag holds
// gates r=0..3 of unit u=4T+q, node n (C layout col=lane&15, row=(lane>>4)*4+reg).
// h/x in LDS as fp32 (cheap writes); bf16 hi/lo built on READ via v_cvt_pk_bf16_f32.
// Gate weights pre-scaled by log2e (i,f,o) / 2*log2e (g) -> activations use raw v_exp_f32.
// fp32 precision via 3-term bf16 split: Ahi*Bhi + Ahi*Blo + Alo*Bhi.
// r12 lesson: 2 groups/wave halved TLP and latency gaps ate the instruction savings;
// 1 group/wave restores 6400 waves (~6.25/SIMD) with the cheaper instruction stream.

typedef __attribute__((ext_vector_type(8))) short s16x8;
typedef __attribute__((ext_vector_type(4))) float fx4;

__device__ __forceinline__ float frcp(float x) { return __builtin_amdgcn_rcpf(x); }
__device__ __forceinline__ float fsig(float x) { return frcp(1.f + __expf(-x)); }
__device__ __forceinline__ float ftanh(float x) { return 1.f - 2.f * frcp(1.f + __expf(2.f * x)); }

__device__ __forceinline__ float exp2p(float x) { float r; asm("v_exp_f32 %0, %1"  : "=v"(r) : "v"(x)); return r; }   // 2^x
__device__ __forceinline__ float exp2m(float x) { float r; asm("v_exp_f32 %0, -%1" : "=v"(r) : "v"(x)); return r; }   // 2^-x
// gp = log2e * g  ->  sigmoid(g)
__device__ __forceinline__ float sigE(float gp)  { return frcp(1.f + exp2m(gp)); }
// gp = 2*log2e * g ->  tanh(g)
__device__ __forceinline__ float tanhE(float gp) { return 1.f - 2.f * frcp(1.f + exp2p(gp)); }

__device__ __forceinline__ unsigned bfhi(float f) {          // RNE f32->bf16 (as u16)
    unsigned b = __float_as_uint(f);
    return (b + 0x7FFFu + ((b >> 16) & 1u)) >> 16;
}
__device__ __forceinline__ float bfval(unsigned h) { return __uint_as_float(h << 16); }

// read 8 fp32 k-elements from LDS, produce bf16 hi + residual-lo fragments
__device__ __forceinline__ void buildB2(const float* L, int q, int n, s16x8& hi, s16x8& lo) {
    float f[8];
#pragma unroll
    for (int e = 0; e < 8; ++e) f[e] = L[(8 * q + e) * 17 + n];   // pairs fuse to ds_read2_b32
    union { unsigned w[4]; s16x8 v; } H, Lo;
#pragma unroll
    for (int i = 0; i < 4; ++i) {
        unsigned hw;
        asm("v_cvt_pk_bf16_f32 %0, %1, %2" : "=v"(hw) : "v"(f[2 * i]), "v"(f[2 * i + 1]));
        const float r0 = f[2 * i]     - __uint_as_float(hw << 16);
        const float r1 = f[2 * i + 1] - __uint_as_float(hw & 0xFFFF0000u);
        unsigned lw;
        asm("v_cvt_pk_bf16_f32 %0, %1, %2" : "=v"(lw) : "v"(r0), "v"(r1));
        H.w[i] = hw; Lo.w[i] = lw;
    }
    hi = H.v; lo = Lo.v;
}

__global__ __launch_bounds__(64, 1) void enc_kernel(
    const float* __restrict__ agent, const float* __restrict__ av,
    const float* __restrict__ oth,   const float* __restrict__ lane,
    const float* __restrict__ agWih, const float* __restrict__ agWhh, const float* __restrict__ agB,
    const float* __restrict__ avWih, const float* __restrict__ avWhh, const float* __restrict__ avB,
    const float* __restrict__ otWih, const float* __restrict__ otWhh, const float* __restrict__ otB,
    float* __restrict__ ws)
{
    __shared__ float hlds[32 * 17];          // [k-slot 0..31][node 0..15], pad 17 words

    const int l = threadIdx.x & 63;
    const int n = l & 15;     // node within group (and A local row, B/D col)
    const int q = l >> 4;     // k-block (and unit offset)
    float* L = hlds;

    const int g0 = blockIdx.x;               // group id 0..6399 (16 nodes each)
    int task;
    if (g0 < 128) task = 0;
    else if (g0 < 256) task = 1;
    else if (g0 < 2304) task = 2;
    else task = 3;                           // lanes use the *agent* encoder (faithful to source bug)

    const float* Whh; const float* Wih; const float* Bp;
    if (task == 1)      { Wih = avWih; Whh = avWhh; Bp = avB; }
    else if (task == 2) { Wih = otWih; Whh = otWhh; Bp = otB; }
    else                { Wih = agWih; Whh = agWhh; Bp = agB; }

    const int node = g0 * 16 + n;
    const float* xp;
    if (task == 0)      xp = agent + node * 100;
    else if (task == 1) xp = av   + (node - 2048)  * 40;
    else if (task == 2) xp = oth  + (node - 4096)  * 40;
    else                xp = lane + (node - 36864) * 40;

    // preload x for steps 5q..5q+4 (lane (n,q) is the step-owner)
    float xv[10];
#pragma unroll
    for (int s = 0; s < 5; ++s) {
        float2 t2 = *reinterpret_cast<const float2*>(xp + 2 * (5 * q + s));
        xv[2 * s] = t2.x; xv[2 * s + 1] = t2.y;
    }

    // ---- A fragments (weights, loop-invariant): 7 tiles x (hi,lo), log2e folded ----
    const float L2E = 1.4426950408889634f;
    s16x8 Ahi[7], Alo[7];
#pragma unroll
    for (int T = 0; T < 7; ++T) {
        const int p = 16 * T + n;            // packed gate row
        const int r = p & 3;
        const int u = p >> 2;
        int row = r * 25 + u;                // torch row
        if (row > 99) row = 99;              // clamp fake rows (u>=25) in-bounds
        const float sc = (r == 2) ? 2.f * L2E : L2E;   // fold log2e (2x for tanh gate)
        float w[8];
        if (q < 3) {
            const float* src = Whh + row * 25 + 8 * q;
#pragma unroll
            for (int e = 0; e < 8; ++e) w[e] = src[e] * sc;
        } else {
            w[0] = Whh[row * 25 + 24] * sc;
            w[1] = Wih[row * 2] * sc;
            w[2] = Wih[row * 2 + 1] * sc;
            w[3] = Bp[row] * sc;
            w[4] = w[5] = w[6] = w[7] = 0.f;
        }
#pragma unroll
        for (int e = 0; e < 8; ++e) {
            unsigned h = bfhi(w[e]);
            unsigned lo = bfhi(w[e] - bfval(h));
            Ahi[T][e] = (short)h;
            Alo[T][e] = (short)lo;
        }
    }

    // ---- init LDS: h(=0) slots, x(0), bias-one, zero pads ----
#pragma unroll
    for (int T = 0; T < 6; ++T) L[(4 * T + q) * 17 + n] = 0.f;
    if (q == 0) {
        L[24 * 17 + n] = 0.f;
        L[25 * 17 + n] = xv[0];
        L[26 * 17 + n] = xv[1];
    }
    if (q == 3) L[27 * 17 + n] = 1.f;
    L[(28 + q) * 17 + n] = 0.f;
    __builtin_amdgcn_wave_barrier();

    s16x8 Bh, Bl;
    buildB2(L, q, n, Bh, Bl);

    float c[7], hv[7];
#pragma unroll
    for (int T = 0; T < 7; ++T) { c[T] = 0.f; hv[T] = 0.f; }

    const fx4 zero4 = {0.f, 0.f, 0.f, 0.f};
    const float TL2E = 2.f * L2E;

#pragma unroll 1
    for (int tt = 0; tt < 4; ++tt) {
#pragma unroll
        for (int s = 0; s < 5; ++s) {
            fx4 acc[7];
#pragma unroll
            for (int T = 0; T < 7; ++T) {
                fx4 a = __builtin_amdgcn_mfma_f32_16x16x32_bf16(Ahi[T], Bh, zero4, 0, 0, 0);
                a = __builtin_amdgcn_mfma_f32_16x16x32_bf16(Ahi[T], Bl, a, 0, 0, 0);
                acc[T] = __builtin_amdgcn_mfma_f32_16x16x32_bf16(Alo[T], Bh, a, 0, 0, 0);
            }
            // cell update: lane owns unit u=4T+q of node n; acc[T] = {i,f,g,o} (pre-scaled by log2e)
#pragma unroll
            for (int T = 0; T < 7; ++T) {
                const float iv = sigE(acc[T][0]);
                const float fv = sigE(acc[T][1]);
                const float gv = tanhE(acc[T][2]);
                const float ov = sigE(acc[T][3]);
                c[T]  = fv * c[T] + iv * gv;
                hv[T] = ov * tanhE(c[T] * TL2E);
            }
            const bool lastStep = (tt == 3) && (s == 4);
            if (!lastStep) {
                // publish h(t+1) as fp32: k=4T+q for T<6, k=24 by q==0 (never touch x/bias slots 25..27)
#pragma unroll
                for (int T = 0; T < 6; ++T) L[(4 * T + q) * 17 + n] = hv[T];
                if (q == 0) L[24 * 17 + n] = hv[6];
                // publish x(t+1) by its owner lane
                if (s < 4) {
                    if (q == tt) {
                        L[25 * 17 + n] = xv[2 * (s + 1)];
                        L[26 * 17 + n] = xv[2 * (s + 1) + 1];
                    }
                } else {
                    if (q == tt + 1) {
                        L[25 * 17 + n] = xv[0];
                        L[26 * 17 + n] = xv[1];
                    }
                }
                __builtin_amdgcn_wave_barrier();
                buildB2(L, q, n, Bh, Bl);
            }
        }
    }

    // ---- store c (and h for agents) ----
    float* dst_c; float* dst_h = nullptr;
    if (task == 0)      { dst_h = ws + node * 25; dst_c = ws + 51200 + node * 25; }
    else if (task == 1) dst_c = ws + 102400 + (node - 2048) * 25;
    else if (task == 2) dst_c = ws + 153600 + (node - 4096) * 25;
    else                dst_c = ws + 972800 + (node - 36864) * 25;
#pragma unroll
    for (int T = 0; T < 7; ++T) {
        const int u = 4 * T + q;
        if (u < 25) {
            dst_c[u] = c[T];
            if (task == 0) dst_h[u] = hv[T];
        }
    }
}

// ---------------- GAT + env_lane_info: one block per env ----------------
__global__ __launch_bounds__(256) void gat_kernel(
    const float* __restrict__ ws,
    const float* __restrict__ gavW, const float* __restrict__ gavAl, const float* __restrict__ gavAr, const float* __restrict__ gavB,
    const float* __restrict__ gotW, const float* __restrict__ gotAl, const float* __restrict__ gotAr, const float* __restrict__ gotB,
    const float* __restrict__ glnW, const float* __restrict__ glnAl, const float* __restrict__ glnAr, const float* __restrict__ glnB,
    float* __restrict__ envcode, float* __restrict__ lane_out)
{
    __shared__ float X[50 * 25];   // 0: ag_c, 1: av_c, 2..17: ot srcs, 18..49: ln srcs
    __shared__ float F[52 * 25];   // 0: fs_av, 1: fd_av(unused), 2: fd_ot, 3: fd_ln, 4..19: fs_ot, 20..51: fs_ln
    __shared__ float er[10];       // [conv(ot=0,ln=1)][head]
    __shared__ float Eo[16 * 5];
    __shared__ float El[32 * 5];

    const int tid = threadIdx.x;
    const int b = blockIdx.x;
    const float* agc = ws + 51200;
    const float* avc = ws + 102400;
    const float* otc = ws + 153600;
    const float* lnc = ws + 972800;

    for (int i = tid; i < 1250; i += 256) {
        int r = i / 25, k = i - r * 25;
        float v;
        if (r == 0)      v = agc[b * 25 + k];
        else if (r == 1) v = avc[b * 25 + k];
        else if (r < 18) v = otc[(b * 16 + (r - 2)) * 25 + k];
        else             v = lnc[(b * 32 + (r - 18)) * 25 + k];
        X[i] = v;
    }
    __syncthreads();

    for (int d = tid; d < 1300; d += 256) {
        int row = d / 25, o = d - row * 25;
        const float* W; const float* xs;
        if (row == 0)      { W = gavW; xs = &X[1 * 25]; }
        else if (row == 1) { W = gavW; xs = &X[0]; }
        else if (row == 2) { W = gotW; xs = &X[0]; }
        else if (row == 3) { W = glnW; xs = &X[0]; }
        else if (row < 20) { W = gotW; xs = &X[(2 + row - 4) * 25]; }
        else               { W = glnW; xs = &X[(18 + row - 20) * 25]; }
        float acc = 0.f;
#pragma unroll
        for (int k = 0; k < 25; ++k) acc += W[o * 25 + k] * xs[k];
        F[row * 25 + o] = acc;
    }
    __syncthreads();

    if (tid < 10) {
        int conv = tid / 5, nn = tid - conv * 5;
        const float* ar = conv ? glnAr : gotAr;
        const float* fd = &F[(2 + conv) * 25];
        float acc = 0.f;
#pragma unroll
        for (int f = 0; f < 5; ++f) acc += fd[nn * 5 + f] * ar[nn * 5 + f];
        er[tid] = acc;
    }
    __syncthreads();

    for (int d = tid; d < 240; d += 256) {
        if (d < 80) {
            int i = d / 5, nn = d - i * 5;
            const float* fsrow = &F[(4 + i) * 25];
            float acc = er[nn];
#pragma unroll
            for (int f = 0; f < 5; ++f) acc += fsrow[nn * 5 + f] * gotAl[nn * 5 + f];
            Eo[d] = (acc > 0.f) ? acc : 0.2f * acc;
        } else {
            int d2 = d - 80;
            int i = d2 / 5, nn = d2 - i * 5;
            const float* fsrow = &F[(20 + i) * 25];
            float acc = er[5 + nn];
#pragma unroll
            for (int f = 0; f < 5; ++f) acc += fsrow[nn * 5 + f] * glnAl[nn * 5 + f];
            El[d2] = (acc > 0.f) ? acc : 0.2f * acc;
        }
    }
    __syncthreads();

    if (tid < 10) {
        int conv = tid / 5, nn = tid - conv * 5;
        if (conv == 0) {
            float m = -1e30f;
            for (int i = 0; i < 16; ++i) m = fmaxf(m, Eo[i * 5 + nn]);
            float s = 0.f;
            for (int i = 0; i < 16; ++i) s += __expf(Eo[i * 5 + nn] - m);
            float inv = frcp(s);
            for (int i = 0; i < 16; ++i) Eo[i * 5 + nn] = __expf(Eo[i * 5 + nn] - m) * inv;
        } else {
            float m = -1e30f;
            for (int i = 0; i < 32; ++i) m = fmaxf(m, El[i * 5 + nn]);
            float s = 0.f;
            for (int i = 0; i < 32; ++i) s += __expf(El[i * 5 + nn] - m);
            float inv = frcp(s);
            for (int i = 0; i < 32; ++i) El[i * 5 + nn] = __expf(El[i * 5 + nn] - m) * inv;
        }
    }
    __syncthreads();

    if (tid < 25) {
        const int o = tid, nn = o / 5;
        float v_av = F[o] + gavB[o];
        float s = 0.f;
        for (int i = 0; i < 16; ++i) s += Eo[i * 5 + nn] * F[(4 + i) * 25 + o];
        float v_ot = s + gotB[o];
        s = 0.f;
        for (int i = 0; i < 32; ++i) s += El[i * 5 + nn] * F[(20 + i) * 25 + o];
        float v_ln = s + glnB[o];
        envcode[b * 25 + o] = (v_av + v_ot + v_ln) * (1.f / 3.f);
        float m = 0.f;
        for (int i = 0; i < 32; ++i) m += X[(18 + i) * 25 + o];
        lane_out[b * 25 + o] = m * (1.f / 32.f);
    }
}

// ---------------- decoder: 25 lanes per env, 2 envs per wave, reg weights ----------------
__global__ __launch_bounds__(256) void dec_kernel(
    const float* __restrict__ ws,
    const float* __restrict__ deWih, const float* __restrict__ deWhh, const float* __restrict__ deB,
    const float* __restrict__ linW,  const float* __restrict__ linB,
    float* __restrict__ out)
{
    __shared__ float hbuf[8][28];
    const int tid  = threadIdx.x;
    const int lane = tid & 63;
    const int half = lane >> 5;
    const int u    = lane & 31;
    const int u2   = (u < 25) ? u : 0;
    const bool act = (u < 25);
    const int wglob = (blockIdx.x * 256 + tid) >> 6;
    const int b = wglob * 2 + half;                 // env id
    const int envloc = ((tid >> 6) << 1) + half;    // 0..7 within block

    float U[4][25], Wi[4], Bb[4];
#pragma unroll
    for (int r = 0; r < 4; ++r) {
        const int row = u2 + 25 * r;
#pragma unroll
        for (int k = 0; k < 25; ++k) U[r][k] = deWhh[row * 25 + k];
        Wi[r] = deWih[row];
        Bb[r] = deB[row];
    }
    const int j = u & 1;
    float lw[25];
#pragma unroll
    for (int k = 0; k < 25; ++k) lw[k] = linW[j * 25 + k];
    const float lb = linB[j];

    const float* agh = ws;
    const float* agc = ws + 51200;
    const float* env = ws + 2611200;

    float h[25];
#pragma unroll
    for (int k = 0; k < 25; ++k) h[k] = agh[b * 25 + k];
    float c_own = agc[b * 25 + u2] + env[b * 25 + u2];

    for (int t = 0; t < 30; ++t) {
        const float tt = 0.1f * (float)t;
        float g[4];
#pragma unroll
        for (int r = 0; r < 4; ++r) {
            float acc = Bb[r] + Wi[r] * tt;
#pragma unroll
            for (int k = 0; k < 25; ++k) acc += U[r][k] * h[k];
            g[r] = acc;
        }
        const float iv = fsig(g[0]);
        const float fv = fsig(g[1]);
        const float gv = ftanh(g[2]);
        const float ov = fsig(g[3]);
        c_own = fv * c_own + iv * gv;
        const float ho = ov * ftanh(c_own);
        if (act) hbuf[envloc][u] = ho;
        __builtin_amdgcn_wave_barrier();   // intra-wave LDS exchange; LDS is in-order per wave
#pragma unroll
        for (int k = 0; k < 25; ++k) h[k] = hbuf[envloc][k];
        float ov2 = lb;
#pragma unroll
        for (int k = 0; k < 25; ++k) ov2 += lw[k] * h[k];
        if (u < 2) out[b * 60 + t * 2 + u] = ov2;
    }
}

// ---------------- launch ----------------
extern "C" void kernel_launch(void* const* d_in, const int* in_sizes, int n_in,
                              void* d_out, int out_size, void* d_ws, size_t ws_size,
                              hipStream_t stream)
{
    const float* agent = (const float*)d_in[0];
    const float* av    = (const float*)d_in[1];
    const float* oth   = (const float*)d_in[2];
    const float* lane  = (const float*)d_in[3];
    const float* agWih = (const float*)d_in[4];
    const float* agWhh = (const float*)d_in[5];
    const float* agB   = (const float*)d_in[6];
    const float* avWih = (const float*)d_in[7];
    const float* avWhh = (const float*)d_in[8];
    const float* avB   = (const float*)d_in[9];
    const float* otWih = (const float*)d_in[10];
    const float* otWhh = (const float*)d_in[11];
    const float* otB   = (const float*)d_in[12];
    const float* deWih = (const float*)d_in[13];
    const float* deWhh = (const float*)d_in[14];
    const float* deB   = (const float*)d_in[15];
    const float* linW  = (const float*)d_in[16];
    const float* linB  = (const float*)d_in[17];
    const float* gavW  = (const float*)d_in[18];
    const float* gavAl = (const float*)d_in[19];
    const float* gavAr = (const float*)d_in[20];
    const float* gavB  = (const float*)d_in[21];
    const float* gotW  = (const float*)d_in[22];
    const float* gotAl = (const float*)d_in[23];
    const float* gotAr = (const float*)d_in[24];
    const float* gotB  = (const float*)d_in[25];
    const float* glnW  = (const float*)d_in[26];
    const float* glnAl = (const float*)d_in[27];
    const float* glnAr = (const float*)d_in[28];
    const float* glnB  = (const float*)d_in[29];
    // d_in[30]=others_dst, d_in[31]=lane_dst: implicit (i/16, i/32), not needed

    float* out = (float*)d_out;
    float* ws  = (float*)d_ws;

    enc_kernel<<<6400, 64, 0, stream>>>(agent, av, oth, lane,
                                        agWih, agWhh, agB,
                                        avWih, avWhh, avB,
                                        otWih, otWhh, otB, ws);

    gat_kernel<<<2048, 256, 0, stream>>>(ws,
                                         gavW, gavAl, gavAr, gavB,
                                         gotW, gotAl, gotAr, gotB,
                                         glnW, glnAl, glnAr, glnB,
                                         ws + 2611200, out + 122880);

    dec_kernel<<<256, 256, 0, stream>>>(ws, deWih, deWhh, deB, linW, linB, out);
}

// Round 14
// 129.727 us; speedup vs baseline: 3.0807x; 1.0260x over previous
//
#include <hip/hip_runtime.h>

// ---------------- constants ----------------
// B=2048, K_OTH=16, K_LANE=32, N_OTH=32768, N_LANE=65536
// node id ranges: [0,2048) agent | [2048,4096) av | [4096,36864) others | [36864,102400) lanes
// ws layout (floats): ag_h @0 | ag_c @51200 | av_c @102400 | ot_c @153600 | ln_c @972800 | env_code @2611200
// out layout: predict [2048*30*2] @0, env_lane_info [2048*25] @122880
//
// enc (MFMA): one wave (64-thr block) owns ONE 16-node group for all 20 steps.
// Gates[112 packed rows][16 nodes] = 7 MFMA tiles (16x16x32 bf16).
// K layout: k<25 = h, k=25,26 = x0,x1, k=27 = 1.0 (bias), k>=28 = 0.
// Packed gate row p = 4u + r <-> torch row r*25 + u; lane (n=l&15,q=l>>4) C-frag holds
// gates r=0..3 of unit u=4T+q, node n (C layout col=lane&15, row=(lane>>4)*4+reg).
// h/x in LDS as fp32; bf16 hi/lo built on READ via v_cvt_pk_bf16_f32.
// Gate weights pre-scaled by log2e (i,f,o) / 2*log2e (g) -> raw v_exp_f32 (2^x).
// fp32 precision via 3-term bf16 split: Ahi*Bhi + Ahi*Blo + Alo*Bhi.
// r14: rcp-fused activations — c' = [c(1+A)(1+C)+(C-1)(1+B)]*rcp((1+A)(1+B)(1+C)),
// h = (E-1)*rcp((1+D)(1+E)); 10 trans/unit-step -> 7 (trans issue ~16cyc dominates).

typedef __attribute__((ext_vector_type(8))) short s16x8;
typedef __attribute__((ext_vector_type(4))) float fx4;

__device__ __forceinline__ float frcp(float x) { return __builtin_amdgcn_rcpf(x); }
__device__ __forceinline__ float fsig(float x) { return frcp(1.f + __expf(-x)); }
__device__ __forceinline__ float ftanh(float x) { return 1.f - 2.f * frcp(1.f + __expf(2.f * x)); }

__device__ __forceinline__ float exp2p(float x) { float r; asm("v_exp_f32 %0, %1"  : "=v"(r) : "v"(x)); return r; }   // 2^x
__device__ __forceinline__ float exp2m(float x) { float r; asm("v_exp_f32 %0, -%1" : "=v"(r) : "v"(x)); return r; }   // 2^-x

__device__ __forceinline__ unsigned bfhi(float f) {          // RNE f32->bf16 (as u16)
    unsigned b = __float_as_uint(f);
    return (b + 0x7FFFu + ((b >> 16) & 1u)) >> 16;
}
__device__ __forceinline__ float bfval(unsigned h) { return __uint_as_float(h << 16); }

// read 8 fp32 k-elements from LDS, produce bf16 hi + residual-lo fragments
__device__ __forceinline__ void buildB2(const float* L, int q, int n, s16x8& hi, s16x8& lo) {
    float f[8];
#pragma unroll
    for (int e = 0; e < 8; ++e) f[e] = L[(8 * q + e) * 17 + n];   // pairs fuse to ds_read2_b32
    union { unsigned w[4]; s16x8 v; } H, Lo;
#pragma unroll
    for (int i = 0; i < 4; ++i) {
        unsigned hw;
        asm("v_cvt_pk_bf16_f32 %0, %1, %2" : "=v"(hw) : "v"(f[2 * i]), "v"(f[2 * i + 1]));
        const float r0 = f[2 * i]     - __uint_as_float(hw << 16);
        const float r1 = f[2 * i + 1] - __uint_as_float(hw & 0xFFFF0000u);
        unsigned lw;
        asm("v_cvt_pk_bf16_f32 %0, %1, %2" : "=v"(lw) : "v"(r0), "v"(r1));
        H.w[i] = hw; Lo.w[i] = lw;
    }
    hi = H.v; lo = Lo.v;
}

__global__ __launch_bounds__(64, 1) void enc_kernel(
    const float* __restrict__ agent, const float* __restrict__ av,
    const float* __restrict__ oth,   const float* __restrict__ lane,
    const float* __restrict__ agWih, const float* __restrict__ agWhh, const float* __restrict__ agB,
    const float* __restrict__ avWih, const float* __restrict__ avWhh, const float* __restrict__ avB,
    const float* __restrict__ otWih, const float* __restrict__ otWhh, const float* __restrict__ otB,
    float* __restrict__ ws)
{
    __shared__ float hlds[32 * 17];          // [k-slot 0..31][node 0..15], pad 17 words

    const int l = threadIdx.x & 63;
    const int n = l & 15;     // node within group (and A local row, B/D col)
    const int q = l >> 4;     // k-block (and unit offset)
    float* L = hlds;

    const int g0 = blockIdx.x;               // group id 0..6399 (16 nodes each)
    int task;
    if (g0 < 128) task = 0;
    else if (g0 < 256) task = 1;
    else if (g0 < 2304) task = 2;
    else task = 3;                           // lanes use the *agent* encoder (faithful to source bug)

    const float* Whh; const float* Wih; const float* Bp;
    if (task == 1)      { Wih = avWih; Whh = avWhh; Bp = avB; }
    else if (task == 2) { Wih = otWih; Whh = otWhh; Bp = otB; }
    else                { Wih = agWih; Whh = agWhh; Bp = agB; }

    const int node = g0 * 16 + n;
    const float* xp;
    if (task == 0)      xp = agent + node * 100;
    else if (task == 1) xp = av   + (node - 2048)  * 40;
    else if (task == 2) xp = oth  + (node - 4096)  * 40;
    else                xp = lane + (node - 36864) * 40;

    // preload x for steps 5q..5q+4 (lane (n,q) is the step-owner)
    float xv[10];
#pragma unroll
    for (int s = 0; s < 5; ++s) {
        float2 t2 = *reinterpret_cast<const float2*>(xp + 2 * (5 * q + s));
        xv[2 * s] = t2.x; xv[2 * s + 1] = t2.y;
    }

    // ---- A fragments (weights, loop-invariant): 7 tiles x (hi,lo), log2e folded ----
    const float L2E = 1.4426950408889634f;
    s16x8 Ahi[7], Alo[7];
#pragma unroll
    for (int T = 0; T < 7; ++T) {
        const int p = 16 * T + n;            // packed gate row
        const int r = p & 3;
        const int u = p >> 2;
        int row = r * 25 + u;                // torch row
        if (row > 99) row = 99;              // clamp fake rows (u>=25) in-bounds
        const float sc = (r == 2) ? 2.f * L2E : L2E;   // fold log2e (2x for tanh gate)
        float w[8];
        if (q < 3) {
            const float* src = Whh + row * 25 + 8 * q;
#pragma unroll
            for (int e = 0; e < 8; ++e) w[e] = src[e] * sc;
        } else {
            w[0] = Whh[row * 25 + 24] * sc;
            w[1] = Wih[row * 2] * sc;
            w[2] = Wih[row * 2 + 1] * sc;
            w[3] = Bp[row] * sc;
            w[4] = w[5] = w[6] = w[7] = 0.f;
        }
#pragma unroll
        for (int e = 0; e < 8; ++e) {
            unsigned h = bfhi(w[e]);
            unsigned lo = bfhi(w[e] - bfval(h));
            Ahi[T][e] = (short)h;
            Alo[T][e] = (short)lo;
        }
    }

    // ---- init LDS: h(=0) slots, x(0), bias-one, zero pads ----
#pragma unroll
    for (int T = 0; T < 6; ++T) L[(4 * T + q) * 17 + n] = 0.f;
    if (q == 0) {
        L[24 * 17 + n] = 0.f;
        L[25 * 17 + n] = xv[0];
        L[26 * 17 + n] = xv[1];
    }
    if (q == 3) L[27 * 17 + n] = 1.f;
    L[(28 + q) * 17 + n] = 0.f;
    __builtin_amdgcn_wave_barrier();

    s16x8 Bh, Bl;
    buildB2(L, q, n, Bh, Bl);

    float c[7], hv[7];
#pragma unroll
    for (int T = 0; T < 7; ++T) { c[T] = 0.f; hv[T] = 0.f; }

    const fx4 zero4 = {0.f, 0.f, 0.f, 0.f};
    const float TL2E = 2.f * L2E;

#pragma unroll 1
    for (int tt = 0; tt < 4; ++tt) {
#pragma unroll
        for (int s = 0; s < 5; ++s) {
            fx4 acc[7];
#pragma unroll
            for (int T = 0; T < 7; ++T) {
                fx4 a = __builtin_amdgcn_mfma_f32_16x16x32_bf16(Ahi[T], Bh, zero4, 0, 0, 0);
                a = __builtin_amdgcn_mfma_f32_16x16x32_bf16(Ahi[T], Bl, a, 0, 0, 0);
                acc[T] = __builtin_amdgcn_mfma_f32_16x16x32_bf16(Alo[T], Bh, a, 0, 0, 0);
            }
            // rcp-fused cell update: lane owns unit u=4T+q of node n; acc[T] = {i,f,g,o} (log2e pre-scaled)
#pragma unroll
            for (int T = 0; T < 7; ++T) {
                const float A  = exp2m(acc[T][0]);   // 2^-i'
                const float Bv = exp2m(acc[T][1]);   // 2^-f'
                const float Cv = exp2p(acc[T][2]);   // 2^(2*log2e*g)
                const float D  = exp2m(acc[T][3]);   // 2^-o'
                const float a1 = 1.f + A;
                const float b1 = 1.f + Bv;
                const float c1 = 1.f + Cv;
                const float cm = Cv - 1.f;
                const float P  = a1 * c1;
                const float t0 = cm * b1;
                const float num = fmaf(c[T], P, t0);
                const float den = P * b1;
                c[T] = num * frcp(den);
                const float E  = exp2p(c[T] * TL2E);
                const float e1 = 1.f + E;
                const float em = E - 1.f;
                const float d1 = 1.f + D;
                hv[T] = em * frcp(d1 * e1);
            }
            const bool lastStep = (tt == 3) && (s == 4);
            if (!lastStep) {
                // publish h(t+1) as fp32: k=4T+q for T<6, k=24 by q==0 (never touch x/bias slots 25..27)
#pragma unroll
                for (int T = 0; T < 6; ++T) L[(4 * T + q) * 17 + n] = hv[T];
                if (q == 0) L[24 * 17 + n] = hv[6];
                // publish x(t+1) by its owner lane
                if (s < 4) {
                    if (q == tt) {
                        L[25 * 17 + n] = xv[2 * (s + 1)];
                        L[26 * 17 + n] = xv[2 * (s + 1) + 1];
                    }
                } else {
                    if (q == tt + 1) {
                        L[25 * 17 + n] = xv[0];
                        L[26 * 17 + n] = xv[1];
                    }
                }
                __builtin_amdgcn_wave_barrier();
                buildB2(L, q, n, Bh, Bl);
            }
        }
    }

    // ---- store c (and h for agents) ----
    float* dst_c; float* dst_h = nullptr;
    if (task == 0)      { dst_h = ws + node * 25; dst_c = ws + 51200 + node * 25; }
    else if (task == 1) dst_c = ws + 102400 + (node - 2048) * 25;
    else if (task == 2) dst_c = ws + 153600 + (node - 4096) * 25;
    else                dst_c = ws + 972800 + (node - 36864) * 25;
#pragma unroll
    for (int T = 0; T < 7; ++T) {
        const int u = 4 * T + q;
        if (u < 25) {
            dst_c[u] = c[T];
            if (task == 0) dst_h[u] = hv[T];
        }
    }
}

// ---------------- GAT + env_lane_info: one block per env ----------------
__global__ __launch_bounds__(256) void gat_kernel(
    const float* __restrict__ ws,
    const float* __restrict__ gavW, const float* __restrict__ gavAl, const float* __restrict__ gavAr, const float* __restrict__ gavB,
    const float* __restrict__ gotW, const float* __restrict__ gotAl, const float* __restrict__ gotAr, const float* __restrict__ gotB,
    const float* __restrict__ glnW, const float* __restrict__ glnAl, const float* __restrict__ glnAr, const float* __restrict__ glnB,
    float* __restrict__ envcode, float* __restrict__ lane_out)
{
    __shared__ float X[50 * 25];   // 0: ag_c, 1: av_c, 2..17: ot srcs, 18..49: ln srcs
    __shared__ float F[52 * 25];   // 0: fs_av, 1: fd_av(unused), 2: fd_ot, 3: fd_ln, 4..19: fs_ot, 20..51: fs_ln
    __shared__ float er[10];       // [conv(ot=0,ln=1)][head]
    __shared__ float Eo[16 * 5];
    __shared__ float El[32 * 5];

    const int tid = threadIdx.x;
    const int b = blockIdx.x;
    const float* agc = ws + 51200;
    const float* avc = ws + 102400;
    const float* otc = ws + 153600;
    const float* lnc = ws + 972800;

    for (int i = tid; i < 1250; i += 256) {
        int r = i / 25, k = i - r * 25;
        float v;
        if (r == 0)      v = agc[b * 25 + k];
        else if (r == 1) v = avc[b * 25 + k];
        else if (r < 18) v = otc[(b * 16 + (r - 2)) * 25 + k];
        else             v = lnc[(b * 32 + (r - 18)) * 25 + k];
        X[i] = v;
    }
    __syncthreads();

    for (int d = tid; d < 1300; d += 256) {
        int row = d / 25, o = d - row * 25;
        const float* W; const float* xs;
        if (row == 0)      { W = gavW; xs = &X[1 * 25]; }
        else if (row == 1) { W = gavW; xs = &X[0]; }
        else if (row == 2) { W = gotW; xs = &X[0]; }
        else if (row == 3) { W = glnW; xs = &X[0]; }
        else if (row < 20) { W = gotW; xs = &X[(2 + row - 4) * 25]; }
        else               { W = glnW; xs = &X[(18 + row - 20) * 25]; }
        float acc = 0.f;
#pragma unroll
        for (int k = 0; k < 25; ++k) acc += W[o * 25 + k] * xs[k];
        F[row * 25 + o] = acc;
    }
    __syncthreads();

    if (tid < 10) {
        int conv = tid / 5, nn = tid - conv * 5;
        const float* ar = conv ? glnAr : gotAr;
        const float* fd = &F[(2 + conv) * 25];
        float acc = 0.f;
#pragma unroll
        for (int f = 0; f < 5; ++f) acc += fd[nn * 5 + f] * ar[nn * 5 + f];
        er[tid] = acc;
    }
    __syncthreads();

    for (int d = tid; d < 240; d += 256) {
        if (d < 80) {
            int i = d / 5, nn = d - i * 5;
            const float* fsrow = &F[(4 + i) * 25];
            float acc = er[nn];
#pragma unroll
            for (int f = 0; f < 5; ++f) acc += fsrow[nn * 5 + f] * gotAl[nn * 5 + f];
            Eo[d] = (acc > 0.f) ? acc : 0.2f * acc;
        } else {
            int d2 = d - 80;
            int i = d2 / 5, nn = d2 - i * 5;
            const float* fsrow = &F[(20 + i) * 25];
            float acc = er[5 + nn];
#pragma unroll
            for (int f = 0; f < 5; ++f) acc += fsrow[nn * 5 + f] * glnAl[nn * 5 + f];
            El[d2] = (acc > 0.f) ? acc : 0.2f * acc;
        }
    }
    __syncthreads();

    if (tid < 10) {
        int conv = tid / 5, nn = tid - conv * 5;
        if (conv == 0) {
            float m = -1e30f;
            for (int i = 0; i < 16; ++i) m = fmaxf(m, Eo[i * 5 + nn]);
            float s = 0.f;
            for (int i = 0; i < 16; ++i) s += __expf(Eo[i * 5 + nn] - m);
            float inv = frcp(s);
            for (int i = 0; i < 16; ++i) Eo[i * 5 + nn] = __expf(Eo[i * 5 + nn] - m) * inv;
        } else {
            float m = -1e30f;
            for (int i = 0; i < 32; ++i) m = fmaxf(m, El[i * 5 + nn]);
            float s = 0.f;
            for (int i = 0; i < 32; ++i) s += __expf(El[i * 5 + nn] - m);
            float inv = frcp(s);
            for (int i = 0; i < 32; ++i) El[i * 5 + nn] = __expf(El[i * 5 + nn] - m) * inv;
        }
    }
    __syncthreads();

    if (tid < 25) {
        const int o = tid, nn = o / 5;
        float v_av = F[o] + gavB[o];
        float s = 0.f;
        for (int i = 0; i < 16; ++i) s += Eo[i * 5 + nn] * F[(4 + i) * 25 + o];
        float v_ot = s + gotB[o];
        s = 0.f;
        for (int i = 0; i < 32; ++i) s += El[i * 5 + nn] * F[(20 + i) * 25 + o];
        float v_ln = s + glnB[o];
        envcode[b * 25 + o] = (v_av + v_ot + v_ln) * (1.f / 3.f);
        float m = 0.f;
        for (int i = 0; i < 32; ++i) m += X[(18 + i) * 25 + o];
        lane_out[b * 25 + o] = m * (1.f / 32.f);
    }
}

// ---------------- decoder: 25 lanes per env, 2 envs per wave, reg weights ----------------
__global__ __launch_bounds__(256) void dec_kernel(
    const float* __restrict__ ws,
    const float* __restrict__ deWih, const float* __restrict__ deWhh, const float* __restrict__ deB,
    const float* __restrict__ linW,  const float* __restrict__ linB,
    float* __restrict__ out)
{
    __shared__ float hbuf[8][28];
    const int tid  = threadIdx.x;
    const int lane = tid & 63;
    const int half = lane >> 5;
    const int u    = lane & 31;
    const int u2   = (u < 25) ? u : 0;
    const bool act = (u < 25);
    const int wglob = (blockIdx.x * 256 + tid) >> 6;
    const int b = wglob * 2 + half;                 // env id
    const int envloc = ((tid >> 6) << 1) + half;    // 0..7 within block

    float U[4][25], Wi[4], Bb[4];
#pragma unroll
    for (int r = 0; r < 4; ++r) {
        const int row = u2 + 25 * r;
#pragma unroll
        for (int k = 0; k < 25; ++k) U[r][k] = deWhh[row * 25 + k];
        Wi[r] = deWih[row];
        Bb[r] = deB[row];
    }
    const int j = u & 1;
    float lw[25];
#pragma unroll
    for (int k = 0; k < 25; ++k) lw[k] = linW[j * 25 + k];
    const float lb = linB[j];

    const float* agh = ws;
    const float* agc = ws + 51200;
    const float* env = ws + 2611200;

    float h[25];
#pragma unroll
    for (int k = 0; k < 25; ++k) h[k] = agh[b * 25 + k];
    float c_own = agc[b * 25 + u2] + env[b * 25 + u2];

    for (int t = 0; t < 30; ++t) {
        const float tt = 0.1f * (float)t;
        float g[4];
#pragma unroll
        for (int r = 0; r < 4; ++r) {
            float acc = Bb[r] + Wi[r] * tt;
#pragma unroll
            for (int k = 0; k < 25; ++k) acc += U[r][k] * h[k];
            g[r] = acc;
        }
        const float iv = fsig(g[0]);
        const float fv = fsig(g[1]);
        const float gv = ftanh(g[2]);
        const float ov = fsig(g[3]);
        c_own = fv * c_own + iv * gv;
        const float ho = ov * ftanh(c_own);
        if (act) hbuf[envloc][u] = ho;
        __builtin_amdgcn_wave_barrier();   // intra-wave LDS exchange; LDS is in-order per wave
#pragma unroll
        for (int k = 0; k < 25; ++k) h[k] = hbuf[envloc][k];
        float ov2 = lb;
#pragma unroll
        for (int k = 0; k < 25; ++k) ov2 += lw[k] * h[k];
        if (u < 2) out[b * 60 + t * 2 + u] = ov2;
    }
}

// ---------------- launch ----------------
extern "C" void kernel_launch(void* const* d_in, const int* in_sizes, int n_in,
                              void* d_out, int out_size, void* d_ws, size_t ws_size,
                              hipStream_t stream)
{
    const float* agent = (const float*)d_in[0];
    const float* av    = (const float*)d_in[1];
    const float* oth   = (const float*)d_in[2];
    const float* lane  = (const float*)d_in[3];
    const float* agWih = (const float*)d_in[4];
    const float* agWhh = (const float*)d_in[5];
    const float* agB   = (const float*)d_in[6];
    const float* avWih = (const float*)d_in[7];
    const float* avWhh = (const float*)d_in[8];
    const float* avB   = (const float*)d_in[9];
    const float* otWih = (const float*)d_in[10];
    const float* otWhh = (const float*)d_in[11];
    const float* otB   = (const float*)d_in[12];
    const float* deWih = (const float*)d_in[13];
    const float* deWhh = (const float*)d_in[14];
    const float* deB   = (const float*)d_in[15];
    const float* linW  = (const float*)d_in[16];
    const float* linB  = (const float*)d_in[17];
    const float* gavW  = (const float*)d_in[18];
    const float* gavAl = (const float*)d_in[19];
    const float* gavAr = (const float*)d_in[20];
    const float* gavB  = (const float*)d_in[21];
    const float* gotW  = (const float*)d_in[22];
    const float* gotAl = (const float*)d_in[23];
    const float* gotAr = (const float*)d_in[24];
    const float* gotB  = (const float*)d_in[25];
    const float* glnW  = (const float*)d_in[26];
    const float* glnAl = (const float*)d_in[27];
    const float* glnAr = (const float*)d_in[28];
    const float* glnB  = (const float*)d_in[29];
    // d_in[30]=others_dst, d_in[31]=lane_dst: implicit (i/16, i/32), not needed

    float* out = (float*)d_out;
    float* ws  = (float*)d_ws;

    enc_kernel<<<6400, 64, 0, stream>>>(agent, av, oth, lane,
                                        agWih, agWhh, agB,
                                        avWih, avWhh, avB,
                                        otWih, otWhh, otB, ws);

    gat_kernel<<<2048, 256, 0, stream>>>(ws,
                                         gavW, gavAl, gavAr, gavB,
                                         gotW, gotAl, gotAr, gotB,
                                         glnW, glnAl, glnAr, glnB,
                                         ws + 2611200, out + 122880);

    dec_kernel<<<256, 256, 0, stream>>>(ws, deWih, deWhh, deB, linW, linB, out);
}